// Round 2
// baseline (26594.757 us; speedup 1.0000x reference)
//
#include <hip/hip_runtime.h>
#include <cstdint>

#define NN 524288       // total nodes = B*S
#define NB 65536        // batch
#define NS 8
#define NF 64
#define NH 256
#define NQ 9
#define NEDGE 2097152
#define NITERS 3

// ---------------- bf16 helpers (bit-level, RNE) ----------------
__device__ __forceinline__ unsigned short f2b(float f) {
    union { float f; unsigned u; } v; v.f = f;
    unsigned u = v.u;
    u += 0x7FFFu + ((u >> 16) & 1u);
    return (unsigned short)(u >> 16);
}
__device__ __forceinline__ float b2f(unsigned short b) {
    union { unsigned u; float f; } v; v.u = ((unsigned)b) << 16;
    return v.f;
}

// ---------------- small elementwise kernels ----------------

__global__ void k_deg_init(float* __restrict__ deg) {
    int n = blockIdx.x * 256 + threadIdx.x;
    deg[n] = 1.0f;                      // self-loop
}

__global__ void k_deg_acc(const int* __restrict__ eidx, float* __restrict__ deg) {
    int e = blockIdx.x * 256 + threadIdx.x;
    atomicAdd(&deg[eidx[NEDGE + e]], 1.0f);
}

__global__ void k_dinv(const float* __restrict__ deg, float* __restrict__ dinv) {
    int n = blockIdx.x * 256 + threadIdx.x;
    dinv[n] = 1.0f / sqrtf(deg[n]);
}

__global__ void k_embed(const float* __restrict__ syn, const float* __restrict__ eW,
                        const float* __restrict__ eb, float* __restrict__ h) {
    int i = blockIdx.x * 256 + threadIdx.x;
    int n = i >> 6, f = i & 63;
    h[i] = syn[n] * eW[f] + eb[f];
}

// agg (aliases h) = self-loop contribution: xw * dinv^2. 4 elems/thread.
__global__ void k_agg_init(const unsigned short* __restrict__ xwb,
                           const float* __restrict__ dinv, float* __restrict__ agg) {
    int i = blockIdx.x * 256 + threadIdx.x;   // one per 4 elems
    int base = i * 4;
    int n = base >> 6;
    float dd = dinv[n]; dd *= dd;
    ushort4 v = *(const ushort4*)(xwb + base);
    float4 o;
    o.x = b2f(v.x) * dd; o.y = b2f(v.y) * dd;
    o.z = b2f(v.z) * dd; o.w = b2f(v.w) * dd;
    *(float4*)(agg + base) = o;
}

// 4 threads per edge, 16 feats each (32 bytes bf16 gather, 16 fp32 atomics)
__global__ void k_scatter(const int* __restrict__ eidx, const unsigned short* __restrict__ xwb,
                          const float* __restrict__ dinv, float* __restrict__ agg) {
    int gid = blockIdx.x * 256 + threadIdx.x;
    int e = gid >> 2, q = gid & 3;
    int s = eidx[e];
    int d = eidx[NEDGE + e];
    float nrm = dinv[s] * dinv[d];
    const uint4* xs = (const uint4*)(xwb + (size_t)s * 64 + q * 16);
    float* ad = agg + (size_t)d * 64 + q * 16;
#pragma unroll
    for (int j = 0; j < 2; ++j) {
        uint4 v = xs[j];
        unsigned w[4] = {v.x, v.y, v.z, v.w};
#pragma unroll
        for (int t = 0; t < 4; ++t) {
            atomicAdd(ad + j * 8 + t * 2 + 0, b2f((unsigned short)(w[t] & 0xFFFFu)) * nrm);
            atomicAdd(ad + j * 8 + t * 2 + 1, b2f((unsigned short)(w[t] >> 16)) * nrm);
        }
    }
}

// in-place h = relu(h + bias)
__global__ void k_bias_relu(float* __restrict__ h, const float* __restrict__ b) {
    int i = blockIdx.x * 256 + threadIdx.x;
    float v = h[i] + b[i & 63];
    h[i] = v > 0.f ? v : 0.f;
}

// ---------------- generic tiled GEMM ----------------
// out[nrows, M] = ACT( in[nrows, K] @ W[K, M] + bias (+ resid) )
// ACT: 0 = none, 1 = relu, 2 = sigmoid. BF16OUT: store bf16 bits instead of fp32.
// Grid: (nrows/64, ceil(M/64)), block 256. Requires K % 64 == 0, nrows % 64 == 0.

template<int K, int M, int ACT, bool RESID, bool BF16OUT>
__global__ __launch_bounds__(256) void k_gemm(const float* __restrict__ in,
                                              const float* __restrict__ W,
                                              const float* __restrict__ bias,
                                              const float* __restrict__ resid,
                                              void* __restrict__ outv) {
    __shared__ float sI[64][68];
    __shared__ float sW[64][68];
    const int tid = threadIdx.x;
    const int rr = tid >> 4, cc = tid & 15;
    const int r0 = rr * 4, c0 = cc * 4;
    const long rowBase = (long)blockIdx.x * 64;
    const int colBase = blockIdx.y * 64;

    float acc[4][4] = {};

    for (int kc = 0; kc < K; kc += 64) {
#pragma unroll
        for (int t = 0; t < 4; ++t) {
            int idx = tid + t * 256;            // 0..1023 float4 slots
            int row = idx >> 4, kq = idx & 15;
            float4 v = *(const float4*)(in + (rowBase + row) * K + kc + kq * 4);
            *(float4*)&sI[row][kq * 4] = v;
        }
        if (M % 64 == 0) {
#pragma unroll
            for (int t = 0; t < 4; ++t) {
                int idx = tid + t * 256;
                int krow = idx >> 4, kq = idx & 15;
                float4 v = *(const float4*)(W + (long)(kc + krow) * M + colBase + kq * 4);
                *(float4*)&sW[krow][kq * 4] = v;
            }
        } else {
#pragma unroll
            for (int t = 0; t < 16; ++t) {
                int idx = tid + t * 256;        // 0..4095 scalar slots
                int krow = idx >> 6, col = idx & 63;
                float v = 0.f;
                if (colBase + col < M) v = W[(long)(kc + krow) * M + colBase + col];
                sW[krow][col] = v;
            }
        }
        __syncthreads();

#pragma unroll 4
        for (int k = 0; k < 64; ++k) {
            const float4 w4 = *(const float4*)&sW[k][c0];
            const float wv[4] = {w4.x, w4.y, w4.z, w4.w};
            float xv[4];
#pragma unroll
            for (int i = 0; i < 4; ++i) xv[i] = sI[r0 + i][k];
#pragma unroll
            for (int i = 0; i < 4; ++i)
#pragma unroll
                for (int j = 0; j < 4; ++j)
                    acc[i][j] += xv[i] * wv[j];
        }
        __syncthreads();
    }

#pragma unroll
    for (int j = 0; j < 4; ++j) {
        int gc = colBase + c0 + j;
        if (gc >= M) continue;
        float bv = bias ? bias[gc] : 0.f;
#pragma unroll
        for (int i = 0; i < 4; ++i) {
            long gr = rowBase + r0 + i;
            float v = acc[i][j] + bv;
            if (RESID) v += resid[gr * M + gc];
            if (ACT == 1) v = v > 0.f ? v : 0.f;
            else if (ACT == 2) v = 1.f / (1.f + expf(-v));
            if (BF16OUT) ((unsigned short*)outv)[gr * M + gc] = f2b(v);
            else         ((float*)outv)[gr * M + gc] = v;
        }
    }
}

// ---------------- launcher ----------------
// Workspace layout (205.5 MB total):
//   h    : NN*64 fp32  (134 MB)  -- also the scatter accumulator (agg aliases h)
//   xwb  : NN*64 bf16  ( 67 MB)  -- GCN product; later reused as fp32 z-scratch
//   deg  : NN fp32 (2 MB), dinv : NN fp32 (2 MB)

extern "C" void kernel_launch(void* const* d_in, const int* in_sizes, int n_in,
                              void* d_out, int out_size, void* d_ws, size_t ws_size,
                              hipStream_t stream) {
    const float* syn  = (const float*)d_in[0];
    const int*   eidx = (const int*)d_in[1];
    const float* embW = (const float*)d_in[3];
    const float* embB = (const float*)d_in[4];
    const float* gcnW = (const float*)d_in[5];
    const float* gcnB = (const float*)d_in[6];
    const float* rW1  = (const float*)d_in[7];
    const float* rB1  = (const float*)d_in[8];
    const float* rW2  = (const float*)d_in[9];
    const float* rB2  = (const float*)d_in[10];
    const float* hW1  = (const float*)d_in[11];
    const float* hB1  = (const float*)d_in[12];
    const float* hW2  = (const float*)d_in[13];
    const float* hB2  = (const float*)d_in[14];
    const float* hW3  = (const float*)d_in[15];
    const float* hB3  = (const float*)d_in[16];
    float* out = (float*)d_out;

    float*          h    = (float*)d_ws;
    unsigned short* xwb  = (unsigned short*)(h + (size_t)NN * 64);
    float*          zbuf = (float*)xwb;                       // 16.7M fp32 capacity
    float*          deg  = (float*)((char*)d_ws + (size_t)NN * 64 * 6);
    float*          dinv = deg + NN;

    k_deg_init<<<NN / 256, 256, 0, stream>>>(deg);
    k_deg_acc<<<NEDGE / 256, 256, 0, stream>>>(eidx, deg);
    k_dinv<<<NN / 256, 256, 0, stream>>>(deg, dinv);
    k_embed<<<NN * 64 / 256, 256, 0, stream>>>(syn, embW, embB, h);

    for (int i = 0; i < NITERS; ++i) {
        // ---- GCN: xwb = h @ W  (bf16), then aggregate into h's storage ----
        k_gemm<64, 64, 0, false, true><<<dim3(NN / 64, 1), 256, 0, stream>>>(
            h, gcnW + (size_t)i * 64 * 64, nullptr, nullptr, xwb);
        k_agg_init<<<NN * 64 / 4 / 256, 256, 0, stream>>>(xwb, dinv, h);
        k_scatter<<<NEDGE * 4 / 256, 256, 0, stream>>>(eidx, xwb, dinv, h);
        k_bias_relu<<<NN * 64 / 256, 256, 0, stream>>>(h, gcnB + (size_t)i * 64);

        // ---- refine MLP, 8 chunks of 65536 rows (z fits in zbuf) ----
        for (int c = 0; c < 8; ++c) {
            float* hc = h + (size_t)c * 65536 * 64;
            k_gemm<64, 256, 1, false, false><<<dim3(65536 / 64, 4), 256, 0, stream>>>(
                hc, rW1 + (size_t)i * 64 * 256, rB1 + (size_t)i * 256, nullptr, zbuf);
            k_gemm<256, 64, 1, true, false><<<dim3(65536 / 64, 1), 256, 0, stream>>>(
                zbuf, rW2 + (size_t)i * 256 * 64, rB2 + (size_t)i * 64, hc, hc);
        }

        // ---- error head, 2 chunks of 32768 shots ----
        for (int c = 0; c < 2; ++c) {
            const float* hc8 = h + (size_t)c * 32768 * 512;
            float* z1 = zbuf;                       // [32768,256] = 8.4M fp32
            float* z2 = zbuf + (size_t)8388608;     // [32768,128] = 4.2M fp32
            k_gemm<512, 256, 1, false, false><<<dim3(32768 / 64, 4), 256, 0, stream>>>(
                hc8, hW1 + (size_t)i * 512 * 256, hB1 + (size_t)i * 256, nullptr, z1);
            k_gemm<256, 128, 1, false, false><<<dim3(32768 / 64, 2), 256, 0, stream>>>(
                z1, hW2 + (size_t)i * 256 * 128, hB2 + (size_t)i * 128, nullptr, z2);
            k_gemm<128, 9, 2, false, false><<<dim3(32768 / 64, 1), 256, 0, stream>>>(
                z2, hW3 + (size_t)i * 128 * 9, hB3 + (size_t)i * 9, nullptr,
                out + ((size_t)i * NB + (size_t)c * 32768) * NQ);
        }
    }
}

// Round 3
// 3335.564 us; speedup vs baseline: 7.9731x; 7.9731x over previous
//
#include <hip/hip_runtime.h>
#include <cstdint>

#define NN 524288       // total nodes = B*S
#define NB 65536        // batch
#define NQ 9
#define NEDGE 2097152
#define NITERS 3

// ---------------- bf16 helpers (bit-level, RNE) ----------------
__device__ __forceinline__ unsigned short f2b(float f) {
    union { float f; unsigned u; } v; v.f = f;
    unsigned u = v.u;
    u += 0x7FFFu + ((u >> 16) & 1u);
    return (unsigned short)(u >> 16);
}
__device__ __forceinline__ float b2f(unsigned short b) {
    union { unsigned u; float f; } v; v.u = ((unsigned)b) << 16;
    return v.f;
}

// ---------------- CSR construction ----------------

__global__ void k_cnt_init(int* __restrict__ cnt) {
    cnt[blockIdx.x * 256 + threadIdx.x] = 0;
}

__global__ void k_hist(const int* __restrict__ eidx, int* __restrict__ cnt) {
    int e = blockIdx.x * 256 + threadIdx.x;
    atomicAdd(&cnt[eidx[NEDGE + e]], 1);
}

// 512 blocks x 256 threads x 4 elems: block-local exclusive scan + dinv
__global__ void k_scan1(const int* __restrict__ cnt, int* __restrict__ rowptr,
                        int* __restrict__ bsum, float* __restrict__ dinv) {
    __shared__ int sd[256];
    int tid = threadIdx.x;
    int base = (blockIdx.x * 256 + tid) * 4;
    int c0 = cnt[base], c1 = cnt[base + 1], c2 = cnt[base + 2], c3 = cnt[base + 3];
    dinv[base]     = rsqrtf(1.f + (float)c0);
    dinv[base + 1] = rsqrtf(1.f + (float)c1);
    dinv[base + 2] = rsqrtf(1.f + (float)c2);
    dinv[base + 3] = rsqrtf(1.f + (float)c3);
    int t = c0 + c1 + c2 + c3;
    sd[tid] = t; __syncthreads();
    for (int o = 1; o < 256; o <<= 1) {
        int v = (tid >= o) ? sd[tid - o] : 0;
        __syncthreads();
        sd[tid] += v;
        __syncthreads();
    }
    int excl = sd[tid] - t;
    rowptr[base]     = excl;
    rowptr[base + 1] = excl + c0;
    rowptr[base + 2] = excl + c0 + c1;
    rowptr[base + 3] = excl + c0 + c1 + c2;
    if (tid == 255) bsum[blockIdx.x] = sd[255];
}

__global__ void k_scan2(int* __restrict__ bsum) {   // 1 block x 512
    __shared__ int sd[512];
    int tid = threadIdx.x;
    int v = bsum[tid];
    sd[tid] = v; __syncthreads();
    for (int o = 1; o < 512; o <<= 1) {
        int u = (tid >= o) ? sd[tid - o] : 0;
        __syncthreads();
        sd[tid] += u;
        __syncthreads();
    }
    bsum[tid] = sd[tid] - v;   // exclusive
}

// 512 blocks x 256 threads x 4 elems: add block offsets, init cursor
__global__ void k_scan3(int* __restrict__ rowptr, const int* __restrict__ bsum,
                        int* __restrict__ cursor) {
    int tid = threadIdx.x;
    int base = (blockIdx.x * 256 + tid) * 4;
    int off = bsum[blockIdx.x];
#pragma unroll
    for (int j = 0; j < 4; ++j) {
        int r = rowptr[base + j] + off;
        rowptr[base + j] = r;
        cursor[base + j] = r;
    }
    if (blockIdx.x == 511 && tid == 255) rowptr[NN] = NEDGE;
}

__global__ void k_fill(const int* __restrict__ eidx, int* __restrict__ cursor,
                       int* __restrict__ srcs) {
    int e = blockIdx.x * 256 + threadIdx.x;
    int s = eidx[e], d = eidx[NEDGE + e];
    int pos = atomicAdd(&cursor[d], 1);
    srcs[pos] = s;
}

// ---------------- embed (bf16 h) ----------------
__global__ void k_embed(const float* __restrict__ syn, const float* __restrict__ eW,
                        const float* __restrict__ eb, unsigned short* __restrict__ hb) {
    int i = blockIdx.x * 256 + threadIdx.x;
    int base = i * 4, n = base >> 6, f = base & 63;
    float s = syn[n];
    ushort4 o;
    o.x = f2b(s * eW[f]     + eb[f]);
    o.y = f2b(s * eW[f + 1] + eb[f + 1]);
    o.z = f2b(s * eW[f + 2] + eb[f + 2]);
    o.w = f2b(s * eW[f + 3] + eb[f + 3]);
    *(ushort4*)&hb[base] = o;
}

// ---------------- CSR gather: agg = D^-1/2 (A+I) D^-1/2 h ----------------
// one wave per node, lane = feature; block 256 = 4 nodes
__global__ void k_gather(const int* __restrict__ rowptr, const int* __restrict__ srcs,
                         const float* __restrict__ dinv, const unsigned short* __restrict__ hb,
                         unsigned short* __restrict__ aggb) {
    int n = blockIdx.x * 4 + (threadIdx.x >> 6);
    int l = threadIdx.x & 63;
    int beg = rowptr[n], end = rowptr[n + 1];
    float dn = dinv[n];
    float acc = b2f(hb[(size_t)n * 64 + l]) * dn;   // self-loop (x dn again below)
    for (int p = beg; p < end; ++p) {
        int s = srcs[p];
        acc += b2f(hb[(size_t)s * 64 + l]) * dinv[s];
    }
    aggb[(size_t)n * 64 + l] = f2b(acc * dn);
}

// ---------------- generic tiled GEMM ----------------
// out[nrows, M] = ACT( in[nrows, K] @ W[K, M] + bias (+ resid[bf16]) )
// ACT: 0 none, 1 relu, 2 sigmoid. BI: bf16 input. BO: bf16 output.
// Grid (nrows/64, ceil(M/64)), block 256. K%64==0, nrows%64==0.

template<int K, int M, int ACT, bool RESID, bool BI, bool BO>
__global__ __launch_bounds__(256) void k_gemm(const void* __restrict__ inv,
                                              const float* __restrict__ W,
                                              const float* __restrict__ bias,
                                              const unsigned short* __restrict__ residb,
                                              void* __restrict__ outv) {
    __shared__ float sI[64][68];
    __shared__ float sW[64][68];
    const int tid = threadIdx.x;
    const int rr = tid >> 4, cc = tid & 15;
    const int r0 = rr * 4, c0 = cc * 4;
    const long rowBase = (long)blockIdx.x * 64;
    const int colBase = blockIdx.y * 64;

    float acc[4][4] = {};

    for (int kc = 0; kc < K; kc += 64) {
        if (BI) {
            const unsigned short* inb = (const unsigned short*)inv;
#pragma unroll
            for (int t = 0; t < 2; ++t) {
                int idx = tid + t * 256;              // 0..511 uint4 slots (8 bf16 each)
                int row = idx >> 3, col8 = (idx & 7) * 8;
                uint4 v = *(const uint4*)(inb + (size_t)(rowBase + row) * K + kc + col8);
                unsigned w[4] = {v.x, v.y, v.z, v.w};
#pragma unroll
                for (int q = 0; q < 4; ++q) {
                    sI[row][col8 + q * 2]     = b2f((unsigned short)(w[q] & 0xFFFFu));
                    sI[row][col8 + q * 2 + 1] = b2f((unsigned short)(w[q] >> 16));
                }
            }
        } else {
            const float* inf = (const float*)inv;
#pragma unroll
            for (int t = 0; t < 4; ++t) {
                int idx = tid + t * 256;
                int row = idx >> 4, kq = idx & 15;
                float4 v = *(const float4*)(inf + (size_t)(rowBase + row) * K + kc + kq * 4);
                *(float4*)&sI[row][kq * 4] = v;
            }
        }
        if (M % 64 == 0) {
#pragma unroll
            for (int t = 0; t < 4; ++t) {
                int idx = tid + t * 256;
                int krow = idx >> 4, kq = idx & 15;
                float4 v = *(const float4*)(W + (long)(kc + krow) * M + colBase + kq * 4);
                *(float4*)&sW[krow][kq * 4] = v;
            }
        } else {
#pragma unroll
            for (int t = 0; t < 16; ++t) {
                int idx = tid + t * 256;
                int krow = idx >> 6, col = idx & 63;
                float v = 0.f;
                if (colBase + col < M) v = W[(long)(kc + krow) * M + colBase + col];
                sW[krow][col] = v;
            }
        }
        __syncthreads();

#pragma unroll 4
        for (int k = 0; k < 64; ++k) {
            const float4 w4 = *(const float4*)&sW[k][c0];
            const float wv[4] = {w4.x, w4.y, w4.z, w4.w};
            float xv[4];
#pragma unroll
            for (int i = 0; i < 4; ++i) xv[i] = sI[r0 + i][k];
#pragma unroll
            for (int i = 0; i < 4; ++i)
#pragma unroll
                for (int j = 0; j < 4; ++j)
                    acc[i][j] += xv[i] * wv[j];
        }
        __syncthreads();
    }

    if (M % 64 == 0) {
#pragma unroll
        for (int i = 0; i < 4; ++i) {
            long gr = rowBase + r0 + i;
            float v[4];
#pragma unroll
            for (int j = 0; j < 4; ++j)
                v[j] = acc[i][j] + (bias ? bias[colBase + c0 + j] : 0.f);
            if (RESID) {
                ushort4 r4 = *(const ushort4*)&residb[gr * M + colBase + c0];
                v[0] += b2f(r4.x); v[1] += b2f(r4.y);
                v[2] += b2f(r4.z); v[3] += b2f(r4.w);
            }
#pragma unroll
            for (int j = 0; j < 4; ++j) {
                if (ACT == 1) v[j] = v[j] > 0.f ? v[j] : 0.f;
                else if (ACT == 2) v[j] = 1.f / (1.f + expf(-v[j]));
            }
            if (BO) {
                ushort4 o;
                o.x = f2b(v[0]); o.y = f2b(v[1]); o.z = f2b(v[2]); o.w = f2b(v[3]);
                *(ushort4*)((unsigned short*)outv + gr * M + colBase + c0) = o;
            } else {
                *(float4*)((float*)outv + gr * M + colBase + c0) =
                    make_float4(v[0], v[1], v[2], v[3]);
            }
        }
    } else {
#pragma unroll
        for (int j = 0; j < 4; ++j) {
            int gc = colBase + c0 + j;
            if (gc >= M) continue;
            float bv = bias ? bias[gc] : 0.f;
#pragma unroll
            for (int i = 0; i < 4; ++i) {
                long gr = rowBase + r0 + i;
                float v = acc[i][j] + bv;
                if (ACT == 1) v = v > 0.f ? v : 0.f;
                else if (ACT == 2) v = 1.f / (1.f + expf(-v));
                ((float*)outv)[gr * M + gc] = v;
            }
        }
    }
}

// ---------------- launcher ----------------
// Workspace (~149 MB):
//   hb   : NN*64 bf16 (67 MB)   node features, persistent
//   zbuf : NN*64 bf16 (67 MB)   agg output / MLP z-scratch (aliased)
//   srcs : NEDGE int  ( 8 MB)   CSR src list sorted by dst
//   rowptr: (NN+256) int, cnt/cursor: NN int, bsum: 512 int, dinv: NN fp32

extern "C" void kernel_launch(void* const* d_in, const int* in_sizes, int n_in,
                              void* d_out, int out_size, void* d_ws, size_t ws_size,
                              hipStream_t stream) {
    const float* syn  = (const float*)d_in[0];
    const int*   eidx = (const int*)d_in[1];
    const float* embW = (const float*)d_in[3];
    const float* embB = (const float*)d_in[4];
    const float* gcnW = (const float*)d_in[5];
    const float* gcnB = (const float*)d_in[6];
    const float* rW1  = (const float*)d_in[7];
    const float* rB1  = (const float*)d_in[8];
    const float* rW2  = (const float*)d_in[9];
    const float* rB2  = (const float*)d_in[10];
    const float* hW1  = (const float*)d_in[11];
    const float* hB1  = (const float*)d_in[12];
    const float* hW2  = (const float*)d_in[13];
    const float* hB2  = (const float*)d_in[14];
    const float* hW3  = (const float*)d_in[15];
    const float* hB3  = (const float*)d_in[16];
    float* out = (float*)d_out;

    unsigned short* hb     = (unsigned short*)d_ws;
    unsigned short* zbuf   = hb + (size_t)NN * 64;          // agg / z scratch
    int*            srcs   = (int*)(zbuf + (size_t)NN * 64);
    int*            rowptr = srcs + NEDGE;
    int*            cnt    = rowptr + NN + 256;              // cursor after scan
    int*            bsum   = cnt + NN;
    float*          dinv   = (float*)(bsum + 512);

    // CSR build
    k_cnt_init<<<NN / 256, 256, 0, stream>>>(cnt);
    k_hist<<<NEDGE / 256, 256, 0, stream>>>(eidx, cnt);
    k_scan1<<<512, 256, 0, stream>>>(cnt, rowptr, bsum, dinv);
    k_scan2<<<1, 512, 0, stream>>>(bsum);
    k_scan3<<<512, 256, 0, stream>>>(rowptr, bsum, cnt);
    k_fill<<<NEDGE / 256, 256, 0, stream>>>(eidx, cnt, srcs);

    k_embed<<<NN * 64 / 1024, 256, 0, stream>>>(syn, embW, embB, hb);

    for (int i = 0; i < NITERS; ++i) {
        // ---- GCN: agg = norm-aggregate(h); h = relu(agg @ W + b) ----
        k_gather<<<NN / 4, 256, 0, stream>>>(rowptr, srcs, dinv, hb, zbuf);
        k_gemm<64, 64, 1, false, true, true><<<dim3(NN / 64, 1), 256, 0, stream>>>(
            zbuf, gcnW + (size_t)i * 64 * 64, gcnB + (size_t)i * 64, nullptr, hb);

        // ---- refine MLP, 4 chunks of 131072 rows (z bf16 fills zbuf exactly) ----
        for (int c = 0; c < 4; ++c) {
            unsigned short* hc = hb + (size_t)c * 131072 * 64;
            k_gemm<64, 256, 1, false, true, true><<<dim3(2048, 4), 256, 0, stream>>>(
                hc, rW1 + (size_t)i * 64 * 256, rB1 + (size_t)i * 256, nullptr, zbuf);
            k_gemm<256, 64, 1, true, true, true><<<dim3(2048, 1), 256, 0, stream>>>(
                zbuf, rW2 + (size_t)i * 256 * 64, rB2 + (size_t)i * 64, hc, hc);
        }

        // ---- error head (single chunk; z1,z2 bf16 in zbuf) ----
        unsigned short* z1 = zbuf;                         // [65536,256] bf16 = 33.5MB
        unsigned short* z2 = zbuf + (size_t)65536 * 256;   // [65536,128] bf16 = 16.8MB
        k_gemm<512, 256, 1, false, true, true><<<dim3(NB / 64, 4), 256, 0, stream>>>(
            hb, hW1 + (size_t)i * 512 * 256, hB1 + (size_t)i * 256, nullptr, z1);
        k_gemm<256, 128, 1, false, true, true><<<dim3(NB / 64, 2), 256, 0, stream>>>(
            z1, hW2 + (size_t)i * 256 * 128, hB2 + (size_t)i * 128, nullptr, z2);
        k_gemm<128, 9, 2, false, true, false><<<dim3(NB / 64, 1), 256, 0, stream>>>(
            z2, hW3 + (size_t)i * 128 * 9, hB3 + (size_t)i * 9, nullptr,
            out + (size_t)i * NB * NQ);
    }
}

// Round 4
// 2643.751 us; speedup vs baseline: 10.0595x; 1.2617x over previous
//
#include <hip/hip_runtime.h>
#include <cstdint>

#define NN 524288       // total nodes = B*S
#define NB 65536        // batch
#define NQ 9
#define NEDGE 2097152
#define NITERS 3

typedef __attribute__((ext_vector_type(8))) short bf16x8;
typedef __attribute__((ext_vector_type(4))) float f32x4;

// ---------------- bf16 helpers (bit-level, RNE) ----------------
__device__ __forceinline__ unsigned short f2b(float f) {
    union { float f; unsigned u; } v; v.f = f;
    unsigned u = v.u;
    u += 0x7FFFu + ((u >> 16) & 1u);
    return (unsigned short)(u >> 16);
}
__device__ __forceinline__ float b2f(unsigned short b) {
    union { unsigned u; float f; } v; v.u = ((unsigned)b) << 16;
    return v.f;
}

// ---------------- CSR construction ----------------

__global__ void k_cnt_init(int* __restrict__ cnt) {
    cnt[blockIdx.x * 256 + threadIdx.x] = 0;
}

__global__ void k_hist(const int* __restrict__ eidx, int* __restrict__ cnt) {
    int e = blockIdx.x * 256 + threadIdx.x;
    atomicAdd(&cnt[eidx[NEDGE + e]], 1);
}

__global__ void k_scan1(const int* __restrict__ cnt, int* __restrict__ rowptr,
                        int* __restrict__ bsum, float* __restrict__ dinv) {
    __shared__ int sd[256];
    int tid = threadIdx.x;
    int base = (blockIdx.x * 256 + tid) * 4;
    int c0 = cnt[base], c1 = cnt[base + 1], c2 = cnt[base + 2], c3 = cnt[base + 3];
    dinv[base]     = rsqrtf(1.f + (float)c0);
    dinv[base + 1] = rsqrtf(1.f + (float)c1);
    dinv[base + 2] = rsqrtf(1.f + (float)c2);
    dinv[base + 3] = rsqrtf(1.f + (float)c3);
    int t = c0 + c1 + c2 + c3;
    sd[tid] = t; __syncthreads();
    for (int o = 1; o < 256; o <<= 1) {
        int v = (tid >= o) ? sd[tid - o] : 0;
        __syncthreads();
        sd[tid] += v;
        __syncthreads();
    }
    int excl = sd[tid] - t;
    rowptr[base]     = excl;
    rowptr[base + 1] = excl + c0;
    rowptr[base + 2] = excl + c0 + c1;
    rowptr[base + 3] = excl + c0 + c1 + c2;
    if (tid == 255) bsum[blockIdx.x] = sd[255];
}

__global__ void k_scan2(int* __restrict__ bsum) {   // 1 block x 512
    __shared__ int sd[512];
    int tid = threadIdx.x;
    int v = bsum[tid];
    sd[tid] = v; __syncthreads();
    for (int o = 1; o < 512; o <<= 1) {
        int u = (tid >= o) ? sd[tid - o] : 0;
        __syncthreads();
        sd[tid] += u;
        __syncthreads();
    }
    bsum[tid] = sd[tid] - v;   // exclusive
}

__global__ void k_scan3(int* __restrict__ rowptr, const int* __restrict__ bsum,
                        int* __restrict__ cursor) {
    int tid = threadIdx.x;
    int base = (blockIdx.x * 256 + tid) * 4;
    int off = bsum[blockIdx.x];
#pragma unroll
    for (int j = 0; j < 4; ++j) {
        int r = rowptr[base + j] + off;
        rowptr[base + j] = r;
        cursor[base + j] = r;
    }
    if (blockIdx.x == 511 && tid == 255) rowptr[NN] = NEDGE;
}

__global__ void k_fill(const int* __restrict__ eidx, int* __restrict__ cursor,
                       int* __restrict__ srcs) {
    int e = blockIdx.x * 256 + threadIdx.x;
    int s = eidx[e], d = eidx[NEDGE + e];
    int pos = atomicAdd(&cursor[d], 1);
    srcs[pos] = s;
}

// ---------------- weight transpose W[K][M] fp32 -> Wt[M][K] bf16 (x3 iters) ----
__global__ void k_trans(const float* __restrict__ W, unsigned short* __restrict__ Wt,
                        int K, int M, int total) {
    int o = blockIdx.x * 256 + threadIdx.x;
    if (o >= total) return;
    int km = K * M;
    int it = o / km;
    int rem = o - it * km;
    int m = rem / K;
    int k = rem - m * K;
    Wt[o] = f2b(W[(size_t)it * km + (size_t)k * M + m]);
}

// ---------------- embed (bf16 h) ----------------
__global__ void k_embed(const float* __restrict__ syn, const float* __restrict__ eW,
                        const float* __restrict__ eb, unsigned short* __restrict__ hb) {
    int i = blockIdx.x * 256 + threadIdx.x;
    int base = i * 4, n = base >> 6, f = base & 63;
    float s = syn[n];
    ushort4 o;
    o.x = f2b(s * eW[f]     + eb[f]);
    o.y = f2b(s * eW[f + 1] + eb[f + 1]);
    o.z = f2b(s * eW[f + 2] + eb[f + 2]);
    o.w = f2b(s * eW[f + 3] + eb[f + 3]);
    *(ushort4*)&hb[base] = o;
}

// ---------------- CSR gather: agg = D^-1/2 (A+I) D^-1/2 h ----------------
// one wave per node, lane = feature; srcs/dinv preloaded into lanes, shfl-broadcast
__global__ void k_gather(const int* __restrict__ rowptr, const int* __restrict__ srcs,
                         const float* __restrict__ dinv, const unsigned short* __restrict__ hb,
                         unsigned short* __restrict__ aggb) {
    int n = blockIdx.x * 4 + (threadIdx.x >> 6);
    int l = threadIdx.x & 63;
    int beg = rowptr[n], end = rowptr[n + 1];
    int deg = end - beg;
    float dn = dinv[n];

    int   sl = (l < deg) ? srcs[beg + l] : 0;
    float wl = (l < deg) ? dinv[sl] : 0.f;

    float acc = b2f(hb[(size_t)n * 64 + l]) * dn;   // self-loop
    int dmain = deg < 64 ? deg : 64;
    for (int p = 0; p < dmain; ++p) {
        int   s = __shfl(sl, p);
        float w = __shfl(wl, p);
        acc += b2f(hb[(size_t)s * 64 + l]) * w;
    }
    for (int p = 64; p < deg; ++p) {               // never taken in practice
        int s = srcs[beg + p];
        acc += b2f(hb[(size_t)s * 64 + l]) * dinv[s];
    }
    aggb[(size_t)n * 64 + l] = f2b(acc * dn);
}

// ---------------- MFMA GEMM ----------------
// out[rows, MW] = ACT( in[rows, K](bf16) @ Wt[MW, K]^T(bf16) + bias (+resid bf16) )
// ACT: 0 none, 1 relu, 2 sigmoid. BO: bf16 out else fp32.
// Wave tile 16 rows x CF*16 cols; block = 4 waves = 64 rows.
// Grid (rows/64, MW_padded/(CF*16)). K % 32 == 0.
// Fragment layout: A[l&15][(l>>4)*8+j], B[(l>>4)*8+j][l&15] (Wt row-contig),
// C: col = l&15, row = (l>>4)*4 + r  [learn_hip m89-verified].

template<int K, int MW, int CF, int ACT, bool RESID, bool BO>
__global__ __launch_bounds__(256) void k_mf(const unsigned short* __restrict__ in,
                                            const unsigned short* __restrict__ Wt,
                                            const float* __restrict__ bias,
                                            const unsigned short* __restrict__ resid,
                                            void* __restrict__ outv) {
    const int tid = threadIdx.x;
    const int wid = tid >> 6, l = tid & 63;
    const int lr = l & 15, lk = (l >> 4) * 8;
    const long rowA = (long)blockIdx.x * 64 + wid * 16 + lr;
    const int colBase = blockIdx.y * (CF * 16);

    f32x4 acc[CF];
#pragma unroll
    for (int cg = 0; cg < CF; ++cg) acc[cg] = (f32x4){0.f, 0.f, 0.f, 0.f};

    const unsigned short* ap = in + rowA * K + lk;

    for (int kc = 0; kc < K; kc += 32) {
        bf16x8 a = *(const bf16x8*)(ap + kc);
#pragma unroll
        for (int cg = 0; cg < CF; ++cg) {
            int c = colBase + cg * 16 + lr;
            if (MW % 16) c = c < MW ? c : MW - 1;     // clamp (masked cols)
            bf16x8 b = *(const bf16x8*)(Wt + (size_t)c * K + kc + lk);
            acc[cg] = __builtin_amdgcn_mfma_f32_16x16x32_bf16(a, b, acc[cg], 0, 0, 0);
        }
    }

    const long rowC0 = (long)blockIdx.x * 64 + wid * 16 + (l >> 4) * 4;
#pragma unroll
    for (int cg = 0; cg < CF; ++cg) {
        int col = colBase + cg * 16 + lr;
        if (MW % 16) { if (col >= MW) continue; }
        float bb = bias[col];
#pragma unroll
        for (int r = 0; r < 4; ++r) {
            long row = rowC0 + r;
            float v = acc[cg][r] + bb;
            if (RESID) v += b2f(resid[row * MW + col]);
            if (ACT == 1) v = v > 0.f ? v : 0.f;
            else if (ACT == 2) v = 1.f / (1.f + expf(-v));
            if (BO) ((unsigned short*)outv)[row * MW + col] = f2b(v);
            else    ((float*)outv)[row * MW + col] = v;
        }
    }
}

// ---------------- launcher ----------------
// Workspace (~150 MB):
//   hb   : NN*64 bf16 (67 MB)   node features, persistent
//   zbuf : NN*64 bf16 (67 MB)   agg output / MLP z-scratch (aliased)
//   srcs : NEDGE int (8.4 MB), rowptr: NN+256, cnt: NN, bsum: 512, dinv: NN f32
//   Wt   : 605568 bf16 (1.2 MB) transposed weights

extern "C" void kernel_launch(void* const* d_in, const int* in_sizes, int n_in,
                              void* d_out, int out_size, void* d_ws, size_t ws_size,
                              hipStream_t stream) {
    const float* syn  = (const float*)d_in[0];
    const int*   eidx = (const int*)d_in[1];
    const float* embW = (const float*)d_in[3];
    const float* embB = (const float*)d_in[4];
    const float* gcnW = (const float*)d_in[5];
    const float* gcnB = (const float*)d_in[6];
    const float* rW1  = (const float*)d_in[7];
    const float* rB1  = (const float*)d_in[8];
    const float* rW2  = (const float*)d_in[9];
    const float* rB2  = (const float*)d_in[10];
    const float* hW1  = (const float*)d_in[11];
    const float* hB1  = (const float*)d_in[12];
    const float* hW2  = (const float*)d_in[13];
    const float* hB2  = (const float*)d_in[14];
    const float* hW3  = (const float*)d_in[15];
    const float* hB3  = (const float*)d_in[16];
    float* out = (float*)d_out;

    unsigned short* hb     = (unsigned short*)d_ws;
    unsigned short* zbuf   = hb + (size_t)NN * 64;
    int*            srcs   = (int*)(zbuf + (size_t)NN * 64);
    int*            rowptr = srcs + NEDGE;
    int*            cnt    = rowptr + NN + 256;
    int*            bsum   = cnt + NN;
    float*          dinv   = (float*)(bsum + 512);
    unsigned short* gcnWt  = (unsigned short*)(dinv + NN);
    unsigned short* rW1t   = gcnWt + 3 * 64 * 64;
    unsigned short* rW2t   = rW1t + 3 * 64 * 256;
    unsigned short* hW1t   = rW2t + 3 * 256 * 64;
    unsigned short* hW2t   = hW1t + 3 * 512 * 256;
    unsigned short* hW3t   = hW2t + 3 * 256 * 128;

    // weight transposes (fp32 [K][M] -> bf16 [M][K], x3 iters each)
    k_trans<<<(3*64*64   + 255)/256, 256, 0, stream>>>(gcnW, gcnWt, 64, 64,  3*64*64);
    k_trans<<<(3*64*256  + 255)/256, 256, 0, stream>>>(rW1,  rW1t,  64, 256, 3*64*256);
    k_trans<<<(3*256*64  + 255)/256, 256, 0, stream>>>(rW2,  rW2t,  256, 64, 3*256*64);
    k_trans<<<(3*512*256 + 255)/256, 256, 0, stream>>>(hW1,  hW1t,  512, 256, 3*512*256);
    k_trans<<<(3*256*128 + 255)/256, 256, 0, stream>>>(hW2,  hW2t,  256, 128, 3*256*128);
    k_trans<<<(3*128*9   + 255)/256, 256, 0, stream>>>(hW3,  hW3t,  128, 9,   3*128*9);

    // CSR build
    k_cnt_init<<<NN / 256, 256, 0, stream>>>(cnt);
    k_hist<<<NEDGE / 256, 256, 0, stream>>>(eidx, cnt);
    k_scan1<<<512, 256, 0, stream>>>(cnt, rowptr, bsum, dinv);
    k_scan2<<<1, 512, 0, stream>>>(bsum);
    k_scan3<<<512, 256, 0, stream>>>(rowptr, bsum, cnt);
    k_fill<<<NEDGE / 256, 256, 0, stream>>>(eidx, cnt, srcs);

    k_embed<<<NN * 64 / 1024, 256, 0, stream>>>(syn, embW, embB, hb);

    for (int i = 0; i < NITERS; ++i) {
        // ---- GCN: agg = aggregate(h) -> zbuf; h = relu(agg @ W + b) ----
        k_gather<<<NN / 4, 256, 0, stream>>>(rowptr, srcs, dinv, hb, zbuf);
        k_mf<64, 64, 4, 1, false, true><<<dim3(NN / 64, 1), 256, 0, stream>>>(
            zbuf, gcnWt + (size_t)i * 64 * 64, gcnB + (size_t)i * 64, nullptr, hb);

        // ---- refine MLP, 4 chunks of 131072 rows (z bf16 fills zbuf) ----
        for (int c = 0; c < 4; ++c) {
            unsigned short* hc = hb + (size_t)c * 131072 * 64;
            k_mf<64, 256, 16, 1, false, true><<<dim3(2048, 1), 256, 0, stream>>>(
                hc, rW1t + (size_t)i * 64 * 256, rB1 + (size_t)i * 256, nullptr, zbuf);
            k_mf<256, 64, 4, 1, true, true><<<dim3(2048, 1), 256, 0, stream>>>(
                zbuf, rW2t + (size_t)i * 256 * 64, rB2 + (size_t)i * 64, hc, hc);
        }

        // ---- error head ----
        unsigned short* z1 = zbuf;                         // [65536,256] bf16
        unsigned short* z2 = zbuf + (size_t)65536 * 256;   // [65536,128] bf16
        k_mf<512, 256, 16, 1, false, true><<<dim3(NB / 64, 1), 256, 0, stream>>>(
            hb, hW1t + (size_t)i * 512 * 256, hB1 + (size_t)i * 256, nullptr, z1);
        k_mf<256, 128, 8, 1, false, true><<<dim3(NB / 64, 1), 256, 0, stream>>>(
            z1, hW2t + (size_t)i * 256 * 128, hB2 + (size_t)i * 128, nullptr, z2);
        k_mf<128, 9, 1, 2, false, false><<<dim3(NB / 64, 1), 256, 0, stream>>>(
            z2, hW3t + (size_t)i * 128 * 9, hB3 + (size_t)i * 9, nullptr,
            out + (size_t)i * NB * NQ);
    }
}

// Round 5
// 1560.104 us; speedup vs baseline: 17.0468x; 1.6946x over previous
//
#include <hip/hip_runtime.h>
#include <cstdint>

#define NN 524288       // total nodes = B*S
#define NB 65536        // batch
#define NQ 9
#define NEDGE 2097152
#define NITERS 3

typedef __attribute__((ext_vector_type(8))) short bf16x8;
typedef __attribute__((ext_vector_type(4))) float f32x4;

// ---------------- bf16 helpers (bit-level, RNE) ----------------
__device__ __forceinline__ unsigned short f2b(float f) {
    union { float f; unsigned u; } v; v.f = f;
    unsigned u = v.u;
    u += 0x7FFFu + ((u >> 16) & 1u);
    return (unsigned short)(u >> 16);
}
__device__ __forceinline__ float b2f(unsigned short b) {
    union { unsigned u; float f; } v; v.u = ((unsigned)b) << 16;
    return v.f;
}
__device__ __forceinline__ float frelu(float v) { return v > 0.f ? v : 0.f; }

// ---------------- CSR construction ----------------

__global__ void k_cnt_init(int* __restrict__ cnt) {
    cnt[blockIdx.x * 256 + threadIdx.x] = 0;
}

__global__ void k_hist(const int* __restrict__ eidx, int* __restrict__ cnt) {
    int e = blockIdx.x * 256 + threadIdx.x;
    atomicAdd(&cnt[eidx[NEDGE + e]], 1);
}

__global__ void k_scan1(const int* __restrict__ cnt, int* __restrict__ rowptr,
                        int* __restrict__ bsum, float* __restrict__ dinv) {
    __shared__ int sd[256];
    int tid = threadIdx.x;
    int base = (blockIdx.x * 256 + tid) * 4;
    int c0 = cnt[base], c1 = cnt[base + 1], c2 = cnt[base + 2], c3 = cnt[base + 3];
    dinv[base]     = rsqrtf(1.f + (float)c0);
    dinv[base + 1] = rsqrtf(1.f + (float)c1);
    dinv[base + 2] = rsqrtf(1.f + (float)c2);
    dinv[base + 3] = rsqrtf(1.f + (float)c3);
    int t = c0 + c1 + c2 + c3;
    sd[tid] = t; __syncthreads();
    for (int o = 1; o < 256; o <<= 1) {
        int v = (tid >= o) ? sd[tid - o] : 0;
        __syncthreads();
        sd[tid] += v;
        __syncthreads();
    }
    int excl = sd[tid] - t;
    rowptr[base]     = excl;
    rowptr[base + 1] = excl + c0;
    rowptr[base + 2] = excl + c0 + c1;
    rowptr[base + 3] = excl + c0 + c1 + c2;
    if (tid == 255) bsum[blockIdx.x] = sd[255];
}

__global__ void k_scan2(int* __restrict__ bsum) {   // 1 block x 512
    __shared__ int sd[512];
    int tid = threadIdx.x;
    int v = bsum[tid];
    sd[tid] = v; __syncthreads();
    for (int o = 1; o < 512; o <<= 1) {
        int u = (tid >= o) ? sd[tid - o] : 0;
        __syncthreads();
        sd[tid] += u;
        __syncthreads();
    }
    bsum[tid] = sd[tid] - v;   // exclusive
}

__global__ void k_scan3(int* __restrict__ rowptr, const int* __restrict__ bsum,
                        int* __restrict__ cursor) {
    int tid = threadIdx.x;
    int base = (blockIdx.x * 256 + tid) * 4;
    int off = bsum[blockIdx.x];
#pragma unroll
    for (int j = 0; j < 4; ++j) {
        int r = rowptr[base + j] + off;
        rowptr[base + j] = r;
        cursor[base + j] = r;
    }
    if (blockIdx.x == 511 && tid == 255) rowptr[NN] = NEDGE;
}

__global__ void k_fill(const int* __restrict__ eidx, int* __restrict__ cursor,
                       int* __restrict__ srcs) {
    int e = blockIdx.x * 256 + threadIdx.x;
    int s = eidx[e], d = eidx[NEDGE + e];
    int pos = atomicAdd(&cursor[d], 1);
    srcs[pos] = s;
}

// ---------------- weight transpose W[K][M] fp32 -> Wt[M][K] bf16 (x3 iters) ----
__global__ void k_trans(const float* __restrict__ W, unsigned short* __restrict__ Wt,
                        int K, int M, int total) {
    int o = blockIdx.x * 256 + threadIdx.x;
    if (o >= total) return;
    int km = K * M;
    int it = o / km;
    int rem = o - it * km;
    int m = rem / K;
    int k = rem - m * K;
    Wt[o] = f2b(W[(size_t)it * km + (size_t)k * M + m]);
}

// ---------------- embed (bf16 h) ----------------
__global__ void k_embed(const float* __restrict__ syn, const float* __restrict__ eW,
                        const float* __restrict__ eb, unsigned short* __restrict__ hb) {
    int i = blockIdx.x * 256 + threadIdx.x;
    int base = i * 4, n = base >> 6, f = base & 63;
    float s = syn[n];
    ushort4 o;
    o.x = f2b(s * eW[f]     + eb[f]);
    o.y = f2b(s * eW[f + 1] + eb[f + 1]);
    o.z = f2b(s * eW[f + 2] + eb[f + 2]);
    o.w = f2b(s * eW[f + 3] + eb[f + 3]);
    *(ushort4*)&hb[base] = o;
}

// ---------------- CSR gather, unroll-4 for MLP ----------------
// one wave per node, lane = feature; srcs/dinv preloaded into lanes,
// 4 independent 128B row loads in flight per iteration.
__global__ void k_gather(const int* __restrict__ rowptr, const int* __restrict__ srcs,
                         const float* __restrict__ dinv, const unsigned short* __restrict__ hb,
                         unsigned short* __restrict__ aggb) {
    int n = blockIdx.x * 4 + (threadIdx.x >> 6);
    int l = threadIdx.x & 63;
    int beg = rowptr[n], end = rowptr[n + 1];
    int deg = end - beg;
    float dn = dinv[n];

    int   sl = (l < deg) ? srcs[beg + l] : n;     // pad: self addr, weight 0
    float wl = (l < deg) ? dinv[sl] : 0.f;

    float acc = b2f(hb[(size_t)n * 64 + l]) * dn;  // self-loop
    int dmain = deg < 64 ? deg : 64;
    for (int p = 0; p < dmain; p += 4) {
        int s0 = __shfl(sl, p),     s1 = __shfl(sl, p + 1);
        int s2 = __shfl(sl, p + 2), s3 = __shfl(sl, p + 3);
        float w0 = __shfl(wl, p),     w1 = __shfl(wl, p + 1);
        float w2 = __shfl(wl, p + 2), w3 = __shfl(wl, p + 3);
        float v0 = b2f(hb[(size_t)s0 * 64 + l]);
        float v1 = b2f(hb[(size_t)s1 * 64 + l]);
        float v2 = b2f(hb[(size_t)s2 * 64 + l]);
        float v3 = b2f(hb[(size_t)s3 * 64 + l]);
        acc += v0 * w0; acc += v1 * w1; acc += v2 * w2; acc += v3 * w3;
    }
    for (int p = 64; p < deg; ++p) {              // vanishingly rare tail
        int s = srcs[beg + p];
        acc += b2f(hb[(size_t)s * 64 + l]) * dinv[s];
    }
    aggb[(size_t)n * 64 + l] = f2b(acc * dn);
}

// =====================================================================
// MFMA orientation used below ("swapped"): first operand A = weights
// (m = out-col), second operand B = activations (n = out-row).
// A-frag: lane supplies A[l&15][(l>>4)*8+j]  -> Wt[m=base+l&15][k] row-contig.
// B-frag: lane supplies B[(l>>4)*8+j][l&15]  -> act[row=base+l&15][k] row-contig.
// C: lane holds m=(l>>4)*4+r (4 consecutive out-cols!), n=l&15
//   -> ushort4 pack per fragment for LDS/global stores.
// =====================================================================

// ---------------- GCN layer: h = relu(agg @ W + b) ----------------
__global__ __launch_bounds__(256) void k_gcn(const unsigned short* __restrict__ agg,
                                             const unsigned short* __restrict__ Wt,
                                             const float* __restrict__ bias,
                                             unsigned short* __restrict__ hb) {
    const int tid = threadIdx.x, wid = tid >> 6, l = tid & 63;
    const int lr = l & 15, lkq = l >> 4;
    const size_t rbase = (size_t)blockIdx.x * 64 + wid * 16;

    f32x4 acc[4];
#pragma unroll
    for (int mg = 0; mg < 4; ++mg) acc[mg] = (f32x4){0.f, 0.f, 0.f, 0.f};

#pragma unroll
    for (int kc = 0; kc < 64; kc += 32) {
        bf16x8 bf = *(const bf16x8*)(agg + (rbase + lr) * 64 + kc + lkq * 8);
#pragma unroll
        for (int mg = 0; mg < 4; ++mg) {
            bf16x8 a = *(const bf16x8*)(Wt + (size_t)(mg * 16 + lr) * 64 + kc + lkq * 8);
            acc[mg] = __builtin_amdgcn_mfma_f32_16x16x32_bf16(a, bf, acc[mg], 0, 0, 0);
        }
    }
#pragma unroll
    for (int mg = 0; mg < 4; ++mg) {
        int m0 = mg * 16 + lkq * 4;
        float4 bb = *(const float4*)(bias + m0);
        ushort4 o;
        o.x = f2b(frelu(acc[mg][0] + bb.x));
        o.y = f2b(frelu(acc[mg][1] + bb.y));
        o.z = f2b(frelu(acc[mg][2] + bb.z));
        o.w = f2b(frelu(acc[mg][3] + bb.w));
        *(ushort4*)(hb + (rbase + lr) * 64 + m0) = o;
    }
}

// ---------------- fused refine: h = relu(h + relu(h@W1+b1)@W2 + b2) ----------
__global__ __launch_bounds__(256) void k_refine(unsigned short* __restrict__ hb,
                                                const unsigned short* __restrict__ W1t, // [256][64]
                                                const float* __restrict__ b1,
                                                const unsigned short* __restrict__ W2t, // [64][256]
                                                const float* __restrict__ b2) {
    __shared__ unsigned short hl[64][88];    // h tile, pad 88 (stride/4 % 32 = 12)
    __shared__ unsigned short zl[64][280];   // z tile, pad 280
    const int tid = threadIdx.x, wid = tid >> 6, l = tid & 63;
    const int lr = l & 15, lkq = l >> 4;
    unsigned short* hrow = hb + (size_t)blockIdx.x * 64 * 64;

    // stage h tile 64x64
#pragma unroll
    for (int t = 0; t < 2; ++t) {
        int idx = tid + t * 256;            // 0..511, 8-elem chunks
        int row = idx >> 3, c8 = (idx & 7) * 8;
        *(bf16x8*)&hl[row][c8] = *(const bf16x8*)(hrow + row * 64 + c8);
    }
    __syncthreads();

    // GEMM1': z[n][m], m in wid*64..+64 (4 mg), n all 64 (4 ng), K=64
    f32x4 acc1[4][4];
#pragma unroll
    for (int mg = 0; mg < 4; ++mg)
#pragma unroll
        for (int ng = 0; ng < 4; ++ng) acc1[mg][ng] = (f32x4){0.f, 0.f, 0.f, 0.f};

#pragma unroll
    for (int kc = 0; kc < 64; kc += 32) {
        bf16x8 bfr[4];
#pragma unroll
        for (int ng = 0; ng < 4; ++ng)
            bfr[ng] = *(const bf16x8*)&hl[ng * 16 + lr][kc + lkq * 8];
#pragma unroll
        for (int mg = 0; mg < 4; ++mg) {
            bf16x8 a = *(const bf16x8*)(W1t + (size_t)(wid * 64 + mg * 16 + lr) * 64 + kc + lkq * 8);
#pragma unroll
            for (int ng = 0; ng < 4; ++ng)
                acc1[mg][ng] = __builtin_amdgcn_mfma_f32_16x16x32_bf16(a, bfr[ng], acc1[mg][ng], 0, 0, 0);
        }
    }
#pragma unroll
    for (int mg = 0; mg < 4; ++mg) {
        int m0 = wid * 64 + mg * 16 + lkq * 4;
        float4 bb = *(const float4*)(b1 + m0);
#pragma unroll
        for (int ng = 0; ng < 4; ++ng) {
            int n = ng * 16 + lr;
            ushort4 o;
            o.x = f2b(frelu(acc1[mg][ng][0] + bb.x));
            o.y = f2b(frelu(acc1[mg][ng][1] + bb.y));
            o.z = f2b(frelu(acc1[mg][ng][2] + bb.z));
            o.w = f2b(frelu(acc1[mg][ng][3] + bb.w));
            *(ushort4*)&zl[n][m0] = o;
        }
    }
    __syncthreads();

    // GEMM2': r[n][m], m all 64 (4 mg), n = wid*16..+16, K=256
    f32x4 acc2[4];
#pragma unroll
    for (int mg = 0; mg < 4; ++mg) acc2[mg] = (f32x4){0.f, 0.f, 0.f, 0.f};
#pragma unroll
    for (int kc = 0; kc < 256; kc += 32) {
        bf16x8 bz = *(const bf16x8*)&zl[wid * 16 + lr][kc + lkq * 8];
#pragma unroll
        for (int mg = 0; mg < 4; ++mg) {
            bf16x8 a = *(const bf16x8*)(W2t + (size_t)(mg * 16 + lr) * 256 + kc + lkq * 8);
            acc2[mg] = __builtin_amdgcn_mfma_f32_16x16x32_bf16(a, bz, acc2[mg], 0, 0, 0);
        }
    }
    {
        int n = wid * 16 + lr;
#pragma unroll
        for (int mg = 0; mg < 4; ++mg) {
            int m0 = mg * 16 + lkq * 4;
            float4 bb = *(const float4*)(b2 + m0);
            ushort4 rs = *(const ushort4*)&hl[n][m0];
            ushort4 o;
            o.x = f2b(frelu(acc2[mg][0] + bb.x + b2f(rs.x)));
            o.y = f2b(frelu(acc2[mg][1] + bb.y + b2f(rs.y)));
            o.z = f2b(frelu(acc2[mg][2] + bb.z + b2f(rs.z)));
            o.w = f2b(frelu(acc2[mg][3] + bb.w + b2f(rs.w)));
            *(ushort4*)(hrow + (size_t)n * 64 + m0) = o;
        }
    }
}

// ---------------- fused head: out = sig(relu(relu(hall@W1)@W2)@W3) ----------
__global__ __launch_bounds__(256) void k_head(const unsigned short* __restrict__ hb,   // [NB][512]
                                              const unsigned short* __restrict__ W1t,  // [256][512]
                                              const float* __restrict__ b1,
                                              const unsigned short* __restrict__ W2t,  // [128][256]
                                              const float* __restrict__ b2,
                                              const unsigned short* __restrict__ W3t,  // [9][128]
                                              const float* __restrict__ b3,
                                              float* __restrict__ out) {
    __shared__ unsigned short z1[64][280];
    __shared__ unsigned short z2[64][152];
    const int tid = threadIdx.x, wid = tid >> 6, l = tid & 63;
    const int lr = l & 15, lkq = l >> 4;
    const unsigned short* hall = hb + (size_t)blockIdx.x * 64 * 512;

    // GEMM1: z1[n][m], m in wid*64..+64, n all 64, K=512
    f32x4 acc1[4][4];
#pragma unroll
    for (int mg = 0; mg < 4; ++mg)
#pragma unroll
        for (int ng = 0; ng < 4; ++ng) acc1[mg][ng] = (f32x4){0.f, 0.f, 0.f, 0.f};

    for (int kc = 0; kc < 512; kc += 32) {
        bf16x8 bfr[4];
#pragma unroll
        for (int ng = 0; ng < 4; ++ng)
            bfr[ng] = *(const bf16x8*)(hall + (size_t)(ng * 16 + lr) * 512 + kc + lkq * 8);
#pragma unroll
        for (int mg = 0; mg < 4; ++mg) {
            bf16x8 a = *(const bf16x8*)(W1t + (size_t)(wid * 64 + mg * 16 + lr) * 512 + kc + lkq * 8);
#pragma unroll
            for (int ng = 0; ng < 4; ++ng)
                acc1[mg][ng] = __builtin_amdgcn_mfma_f32_16x16x32_bf16(a, bfr[ng], acc1[mg][ng], 0, 0, 0);
        }
    }
#pragma unroll
    for (int mg = 0; mg < 4; ++mg) {
        int m0 = wid * 64 + mg * 16 + lkq * 4;
        float4 bb = *(const float4*)(b1 + m0);
#pragma unroll
        for (int ng = 0; ng < 4; ++ng) {
            int n = ng * 16 + lr;
            ushort4 o;
            o.x = f2b(frelu(acc1[mg][ng][0] + bb.x));
            o.y = f2b(frelu(acc1[mg][ng][1] + bb.y));
            o.z = f2b(frelu(acc1[mg][ng][2] + bb.z));
            o.w = f2b(frelu(acc1[mg][ng][3] + bb.w));
            *(ushort4*)&z1[n][m0] = o;
        }
    }
    __syncthreads();

    // GEMM2: z2[n][m], m in wid*32..+32 (2 mg), n all 64, K=256
    f32x4 acc2[2][4];
#pragma unroll
    for (int mg = 0; mg < 2; ++mg)
#pragma unroll
        for (int ng = 0; ng < 4; ++ng) acc2[mg][ng] = (f32x4){0.f, 0.f, 0.f, 0.f};
#pragma unroll
    for (int kc = 0; kc < 256; kc += 32) {
        bf16x8 bfr[4];
#pragma unroll
        for (int ng = 0; ng < 4; ++ng)
            bfr[ng] = *(const bf16x8*)&z1[ng * 16 + lr][kc + lkq * 8];
#pragma unroll
        for (int mg = 0; mg < 2; ++mg) {
            bf16x8 a = *(const bf16x8*)(W2t + (size_t)(wid * 32 + mg * 16 + lr) * 256 + kc + lkq * 8);
#pragma unroll
            for (int ng = 0; ng < 4; ++ng)
                acc2[mg][ng] = __builtin_amdgcn_mfma_f32_16x16x32_bf16(a, bfr[ng], acc2[mg][ng], 0, 0, 0);
        }
    }
#pragma unroll
    for (int mg = 0; mg < 2; ++mg) {
        int m0 = wid * 32 + mg * 16 + lkq * 4;
        float4 bb = *(const float4*)(b2 + m0);
#pragma unroll
        for (int ng = 0; ng < 4; ++ng) {
            int n = ng * 16 + lr;
            ushort4 o;
            o.x = f2b(frelu(acc2[mg][ng][0] + bb.x));
            o.y = f2b(frelu(acc2[mg][ng][1] + bb.y));
            o.z = f2b(frelu(acc2[mg][ng][2] + bb.z));
            o.w = f2b(frelu(acc2[mg][ng][3] + bb.w));
            *(ushort4*)&z2[n][m0] = o;
        }
    }
    __syncthreads();

    // GEMM3: out[n][m<9], wave owns n = wid*16..+16, K=128
    f32x4 acc3 = (f32x4){0.f, 0.f, 0.f, 0.f};
    int arow = lr < 9 ? lr : 8;
#pragma unroll
    for (int kc = 0; kc < 128; kc += 32) {
        bf16x8 bz = *(const bf16x8*)&z2[wid * 16 + lr][kc + lkq * 8];
        bf16x8 a = *(const bf16x8*)(W3t + (size_t)arow * 128 + kc + lkq * 8);
        acc3 = __builtin_amdgcn_mfma_f32_16x16x32_bf16(a, bz, acc3, 0, 0, 0);
    }
    {
        long shot = (long)blockIdx.x * 64 + wid * 16 + lr;
#pragma unroll
        for (int r = 0; r < 4; ++r) {
            int m = lkq * 4 + r;
            if (m < 9) {
                float v = acc3[r] + b3[m];
                out[shot * 9 + m] = 1.f / (1.f + expf(-v));
            }
        }
    }
}

// ---------------- launcher ----------------
// Workspace (~150 MB): hb 67MB | agg 67MB | srcs 8.4MB | rowptr/cnt/bsum/dinv | Wt 1.2MB

extern "C" void kernel_launch(void* const* d_in, const int* in_sizes, int n_in,
                              void* d_out, int out_size, void* d_ws, size_t ws_size,
                              hipStream_t stream) {
    const float* syn  = (const float*)d_in[0];
    const int*   eidx = (const int*)d_in[1];
    const float* embW = (const float*)d_in[3];
    const float* embB = (const float*)d_in[4];
    const float* gcnW = (const float*)d_in[5];
    const float* gcnB = (const float*)d_in[6];
    const float* rW1  = (const float*)d_in[7];
    const float* rB1  = (const float*)d_in[8];
    const float* rW2  = (const float*)d_in[9];
    const float* rB2  = (const float*)d_in[10];
    const float* hW1  = (const float*)d_in[11];
    const float* hB1  = (const float*)d_in[12];
    const float* hW2  = (const float*)d_in[13];
    const float* hB2  = (const float*)d_in[14];
    const float* hW3  = (const float*)d_in[15];
    const float* hB3  = (const float*)d_in[16];
    float* out = (float*)d_out;

    unsigned short* hb     = (unsigned short*)d_ws;
    unsigned short* agg    = hb + (size_t)NN * 64;
    int*            srcs   = (int*)(agg + (size_t)NN * 64);
    int*            rowptr = srcs + NEDGE;
    int*            cnt    = rowptr + NN + 256;
    int*            bsum   = cnt + NN;
    float*          dinv   = (float*)(bsum + 512);
    unsigned short* gcnWt  = (unsigned short*)(dinv + NN);
    unsigned short* rW1t   = gcnWt + 3 * 64 * 64;
    unsigned short* rW2t   = rW1t + 3 * 64 * 256;
    unsigned short* hW1t   = rW2t + 3 * 256 * 64;
    unsigned short* hW2t   = hW1t + 3 * 512 * 256;
    unsigned short* hW3t   = hW2t + 3 * 256 * 128;

    // weight transposes (fp32 [K][M] -> bf16 [M][K], x3 iters each)
    k_trans<<<(3*64*64   + 255)/256, 256, 0, stream>>>(gcnW, gcnWt, 64, 64,  3*64*64);
    k_trans<<<(3*64*256  + 255)/256, 256, 0, stream>>>(rW1,  rW1t,  64, 256, 3*64*256);
    k_trans<<<(3*256*64  + 255)/256, 256, 0, stream>>>(rW2,  rW2t,  256, 64, 3*256*64);
    k_trans<<<(3*512*256 + 255)/256, 256, 0, stream>>>(hW1,  hW1t,  512, 256, 3*512*256);
    k_trans<<<(3*256*128 + 255)/256, 256, 0, stream>>>(hW2,  hW2t,  256, 128, 3*256*128);
    k_trans<<<(3*128*9   + 255)/256, 256, 0, stream>>>(hW3,  hW3t,  128, 9,   3*128*9);

    // CSR build
    k_cnt_init<<<NN / 256, 256, 0, stream>>>(cnt);
    k_hist<<<NEDGE / 256, 256, 0, stream>>>(eidx, cnt);
    k_scan1<<<512, 256, 0, stream>>>(cnt, rowptr, bsum, dinv);
    k_scan2<<<1, 512, 0, stream>>>(bsum);
    k_scan3<<<512, 256, 0, stream>>>(rowptr, bsum, cnt);
    k_fill<<<NEDGE / 256, 256, 0, stream>>>(eidx, cnt, srcs);

    k_embed<<<NN * 64 / 1024, 256, 0, stream>>>(syn, embW, embB, hb);

    for (int i = 0; i < NITERS; ++i) {
        k_gather<<<NN / 4, 256, 0, stream>>>(rowptr, srcs, dinv, hb, agg);
        k_gcn<<<NN / 64, 256, 0, stream>>>(agg, gcnWt + (size_t)i * 64 * 64,
                                           gcnB + (size_t)i * 64, hb);
        k_refine<<<NN / 64, 256, 0, stream>>>(hb,
                                              rW1t + (size_t)i * 64 * 256, rB1 + (size_t)i * 256,
                                              rW2t + (size_t)i * 256 * 64, rB2 + (size_t)i * 64);
        k_head<<<NB / 64, 256, 0, stream>>>(hb,
                                            hW1t + (size_t)i * 512 * 256, hB1 + (size_t)i * 256,
                                            hW2t + (size_t)i * 256 * 128, hB2 + (size_t)i * 128,
                                            hW3t + (size_t)i * 128 * 9,   hB3 + (size_t)i * 9,
                                            out + (size_t)i * NB * NQ);
    }
}

// Round 6
// 1361.494 us; speedup vs baseline: 19.5335x; 1.1459x over previous
//
#include <hip/hip_runtime.h>
#include <cstdint>

#define NN 524288       // total nodes = B*S
#define NB 65536        // batch
#define NQ 9
#define NEDGE 2097152
#define NITERS 3

typedef __attribute__((ext_vector_type(8))) short bf16x8;
typedef __attribute__((ext_vector_type(4))) float f32x4;

// ---------------- bf16 helpers (bit-level, RNE) ----------------
__device__ __forceinline__ unsigned short f2b(float f) {
    union { float f; unsigned u; } v; v.f = f;
    unsigned u = v.u;
    u += 0x7FFFu + ((u >> 16) & 1u);
    return (unsigned short)(u >> 16);
}
__device__ __forceinline__ float b2f(unsigned short b) {
    union { unsigned u; float f; } v; v.u = ((unsigned)b) << 16;
    return v.f;
}
__device__ __forceinline__ float frelu(float v) { return v > 0.f ? v : 0.f; }

// Swizzled LDS index (ushort units): XOR row&7 into byte bits 4..6.
// Makes 16-rows-at-same-column ds_read_b128 2-way instead of 16-way.
__device__ __forceinline__ int sw64(int r, int c)  { return r * 64  + (c ^ ((r & 7) << 3)); }
__device__ __forceinline__ int sw256(int r, int c) { return r * 256 + (c ^ ((r & 7) << 3)); }

// ---------------- CSR construction ----------------

__global__ void k_cnt_init(int* __restrict__ cnt) {
    cnt[blockIdx.x * 256 + threadIdx.x] = 0;
}

__global__ void k_hist(const int* __restrict__ eidx, int* __restrict__ cnt) {
    int e = blockIdx.x * 256 + threadIdx.x;
    atomicAdd(&cnt[eidx[NEDGE + e]], 1);
}

__global__ void k_scan1(const int* __restrict__ cnt, int* __restrict__ rowptr,
                        int* __restrict__ bsum, float* __restrict__ dinv) {
    __shared__ int sd[256];
    int tid = threadIdx.x;
    int base = (blockIdx.x * 256 + tid) * 4;
    int c0 = cnt[base], c1 = cnt[base + 1], c2 = cnt[base + 2], c3 = cnt[base + 3];
    dinv[base]     = rsqrtf(1.f + (float)c0);
    dinv[base + 1] = rsqrtf(1.f + (float)c1);
    dinv[base + 2] = rsqrtf(1.f + (float)c2);
    dinv[base + 3] = rsqrtf(1.f + (float)c3);
    int t = c0 + c1 + c2 + c3;
    sd[tid] = t; __syncthreads();
    for (int o = 1; o < 256; o <<= 1) {
        int v = (tid >= o) ? sd[tid - o] : 0;
        __syncthreads();
        sd[tid] += v;
        __syncthreads();
    }
    int excl = sd[tid] - t;
    rowptr[base]     = excl;
    rowptr[base + 1] = excl + c0;
    rowptr[base + 2] = excl + c0 + c1;
    rowptr[base + 3] = excl + c0 + c1 + c2;
    if (tid == 255) bsum[blockIdx.x] = sd[255];
}

__global__ void k_scan2(int* __restrict__ bsum) {   // 1 block x 512
    __shared__ int sd[512];
    int tid = threadIdx.x;
    int v = bsum[tid];
    sd[tid] = v; __syncthreads();
    for (int o = 1; o < 512; o <<= 1) {
        int u = (tid >= o) ? sd[tid - o] : 0;
        __syncthreads();
        sd[tid] += u;
        __syncthreads();
    }
    bsum[tid] = sd[tid] - v;   // exclusive
}

__global__ void k_scan3(int* __restrict__ rowptr, const int* __restrict__ bsum,
                        int* __restrict__ cursor) {
    int tid = threadIdx.x;
    int base = (blockIdx.x * 256 + tid) * 4;
    int off = bsum[blockIdx.x];
#pragma unroll
    for (int j = 0; j < 4; ++j) {
        int r = rowptr[base + j] + off;
        rowptr[base + j] = r;
        cursor[base + j] = r;
    }
    if (blockIdx.x == 511 && tid == 255) rowptr[NN] = NEDGE;
}

__global__ void k_fill(const int* __restrict__ eidx, int* __restrict__ cursor,
                       int* __restrict__ srcs) {
    int e = blockIdx.x * 256 + threadIdx.x;
    int s = eidx[e], d = eidx[NEDGE + e];
    int pos = atomicAdd(&cursor[d], 1);
    srcs[pos] = s;
}

// ---------------- weight transpose W[K][M] fp32 -> Wt[M][K] bf16 (x3 iters) ----
__global__ void k_trans(const float* __restrict__ W, unsigned short* __restrict__ Wt,
                        int K, int M, int total) {
    int o = blockIdx.x * 256 + threadIdx.x;
    if (o >= total) return;
    int km = K * M;
    int it = o / km;
    int rem = o - it * km;
    int m = rem / K;
    int k = rem - m * K;
    Wt[o] = f2b(W[(size_t)it * km + (size_t)k * M + m]);
}

// =====================================================================
// Swapped MFMA orientation: A = weights (m = out-col), B = activations
// (n = out-row).  A-frag: Wt[m=base+l&15][kc+(l>>4)*8..+8] row-contig.
// B-frag: act[n=base+l&15][kc+(l>>4)*8..+8] row-contig.
// C: lane holds m=(l>>4)*4+r (4 consecutive out-cols), n=l&15.
// =====================================================================

// ---------------- fused gather + GCN + refine (+ embed for iter 0) --------
// Block = 64 nodes.  LDS: tl 8KB (agg tile, then h tile) + zl 32KB = 40KB.
// h_next = relu(h' + relu(h'@W1+b1)@W2 + b2), h' = relu(agg@Wg+bg),
// agg = D^-1/2 (A+I) D^-1/2 h_prev  (h_prev = syn*eW+eb when EMBED).

template<bool EMBED>
__global__ __launch_bounds__(256, 4) void k_gcnref(
    const int* __restrict__ rowptr, const int* __restrict__ srcs,
    const float* __restrict__ dinv,
    const float* __restrict__ syn, const float* __restrict__ embW,
    const float* __restrict__ embB,
    const unsigned short* __restrict__ hin,
    const unsigned short* __restrict__ Wgt, const float* __restrict__ bg,
    const unsigned short* __restrict__ W1t, const float* __restrict__ b1,
    const unsigned short* __restrict__ W2t, const float* __restrict__ b2,
    unsigned short* __restrict__ hout)
{
    __shared__ unsigned short tl[64 * 64];    // agg tile, then h tile (swizzled)
    __shared__ unsigned short zl[64 * 256];   // z tile (swizzled)
    const int tid = threadIdx.x, wid = tid >> 6, l = tid & 63;
    const int lr = l & 15, lkq = l >> 4;
    const int rowBase = blockIdx.x * 64;

    float ew = 0.f, ebv = 0.f;
    if (EMBED) { ew = embW[l]; ebv = embB[l]; }

    // ---- gather: wave owns rows wid*16..+16, processes 4 nodes in flight ----
    const int nb = rowBase + wid * 16;
    for (int g = 0; g < 4; ++g) {
        const int jn = nb + g * 4 + lkq;          // node this lane preloads for
        int beg = rowptr[jn];
        int dgl = rowptr[jn + 1] - beg;
        int   sl = (lr < dgl) ? srcs[beg + lr] : jn;
        float wl = (lr < dgl) ? dinv[sl] : 0.f;

        int n0 = nb + g * 4;
        float d0 = dinv[n0], d1 = dinv[n0 + 1], d2 = dinv[n0 + 2], d3 = dinv[n0 + 3];
        float a0, a1, a2, a3;
        if (EMBED) {
            a0 = (syn[n0] * ew + ebv) * d0;
            a1 = (syn[n0 + 1] * ew + ebv) * d1;
            a2 = (syn[n0 + 2] * ew + ebv) * d2;
            a3 = (syn[n0 + 3] * ew + ebv) * d3;
        } else {
            a0 = b2f(hin[(size_t)n0 * 64 + l]) * d0;
            a1 = b2f(hin[(size_t)(n0 + 1) * 64 + l]) * d1;
            a2 = b2f(hin[(size_t)(n0 + 2) * 64 + l]) * d2;
            a3 = b2f(hin[(size_t)(n0 + 3) * 64 + l]) * d3;
        }
        int dg0 = __shfl(dgl, 0), dg1 = __shfl(dgl, 16);
        int dg2 = __shfl(dgl, 32), dg3 = __shfl(dgl, 48);
        int dmax = max(max(dg0, dg1), max(dg2, dg3));
        int dfast = dmax < 16 ? dmax : 16;
        for (int p = 0; p < dfast; ++p) {
            int s0 = __shfl(sl, p),      s1 = __shfl(sl, 16 + p);
            int s2 = __shfl(sl, 32 + p), s3 = __shfl(sl, 48 + p);
            float w0 = __shfl(wl, p),      w1 = __shfl(wl, 16 + p);
            float w2 = __shfl(wl, 32 + p), w3 = __shfl(wl, 48 + p);
            float v0, v1, v2, v3;
            if (EMBED) {
                v0 = syn[s0] * ew + ebv; v1 = syn[s1] * ew + ebv;
                v2 = syn[s2] * ew + ebv; v3 = syn[s3] * ew + ebv;
            } else {
                v0 = b2f(hin[(size_t)s0 * 64 + l]);
                v1 = b2f(hin[(size_t)s1 * 64 + l]);
                v2 = b2f(hin[(size_t)s2 * 64 + l]);
                v3 = b2f(hin[(size_t)s3 * 64 + l]);
            }
            a0 += v0 * w0; a1 += v1 * w1; a2 += v2 * w2; a3 += v3 * w3;
        }
        if (dmax > 16) {                           // vanishingly rare tail
            int b0 = __shfl(beg, 0), b1_ = __shfl(beg, 16);
            int b2_ = __shfl(beg, 32), b3_ = __shfl(beg, 48);
            for (int p = 16; p < dg0; ++p) { int s = srcs[b0 + p];
                a0 += (EMBED ? syn[s] * ew + ebv : b2f(hin[(size_t)s * 64 + l])) * dinv[s]; }
            for (int p = 16; p < dg1; ++p) { int s = srcs[b1_ + p];
                a1 += (EMBED ? syn[s] * ew + ebv : b2f(hin[(size_t)s * 64 + l])) * dinv[s]; }
            for (int p = 16; p < dg2; ++p) { int s = srcs[b2_ + p];
                a2 += (EMBED ? syn[s] * ew + ebv : b2f(hin[(size_t)s * 64 + l])) * dinv[s]; }
            for (int p = 16; p < dg3; ++p) { int s = srcs[b3_ + p];
                a3 += (EMBED ? syn[s] * ew + ebv : b2f(hin[(size_t)s * 64 + l])) * dinv[s]; }
        }
        tl[sw64(wid * 16 + g * 4 + 0, l)] = f2b(a0 * d0);
        tl[sw64(wid * 16 + g * 4 + 1, l)] = f2b(a1 * d1);
        tl[sw64(wid * 16 + g * 4 + 2, l)] = f2b(a2 * d2);
        tl[sw64(wid * 16 + g * 4 + 3, l)] = f2b(a3 * d3);
    }
    __syncthreads();

    // ---- GCN: h' = relu(agg @ Wg + bg); wave computes rows wid*16..+16 ----
    f32x4 ag[4];
#pragma unroll
    for (int mg = 0; mg < 4; ++mg) ag[mg] = (f32x4){0.f, 0.f, 0.f, 0.f};
#pragma unroll
    for (int kc = 0; kc < 64; kc += 32) {
        bf16x8 bfr = *(const bf16x8*)&tl[sw64(wid * 16 + lr, kc + lkq * 8)];
#pragma unroll
        for (int mg = 0; mg < 4; ++mg) {
            bf16x8 a = *(const bf16x8*)(Wgt + (size_t)(mg * 16 + lr) * 64 + kc + lkq * 8);
            ag[mg] = __builtin_amdgcn_mfma_f32_16x16x32_bf16(a, bfr, ag[mg], 0, 0, 0);
        }
    }
    __syncthreads();                               // all agg reads done
#pragma unroll
    for (int mg = 0; mg < 4; ++mg) {
        int m0 = mg * 16 + lkq * 4;
        float4 bb = *(const float4*)(bg + m0);
        ushort4 o;
        o.x = f2b(frelu(ag[mg][0] + bb.x));
        o.y = f2b(frelu(ag[mg][1] + bb.y));
        o.z = f2b(frelu(ag[mg][2] + bb.z));
        o.w = f2b(frelu(ag[mg][3] + bb.w));
        *(ushort4*)&tl[sw64(wid * 16 + lr, m0)] = o;   // overwrite tile with h'
    }
    __syncthreads();

    // ---- R1: z = relu(h' @ W1 + b1); wave computes m wid*64..+64, all n ----
    f32x4 z1a[4][4];
#pragma unroll
    for (int mg = 0; mg < 4; ++mg)
#pragma unroll
        for (int ng = 0; ng < 4; ++ng) z1a[mg][ng] = (f32x4){0.f, 0.f, 0.f, 0.f};
#pragma unroll
    for (int kc = 0; kc < 64; kc += 32) {
        bf16x8 bfr[4];
#pragma unroll
        for (int ng = 0; ng < 4; ++ng)
            bfr[ng] = *(const bf16x8*)&tl[sw64(ng * 16 + lr, kc + lkq * 8)];
#pragma unroll
        for (int mg = 0; mg < 4; ++mg) {
            bf16x8 a = *(const bf16x8*)(W1t + (size_t)(wid * 64 + mg * 16 + lr) * 64 + kc + lkq * 8);
#pragma unroll
            for (int ng = 0; ng < 4; ++ng)
                z1a[mg][ng] = __builtin_amdgcn_mfma_f32_16x16x32_bf16(a, bfr[ng], z1a[mg][ng], 0, 0, 0);
        }
    }
#pragma unroll
    for (int mg = 0; mg < 4; ++mg) {
        int m0 = wid * 64 + mg * 16 + lkq * 4;
        float4 bb = *(const float4*)(b1 + m0);
#pragma unroll
        for (int ng = 0; ng < 4; ++ng) {
            int n = ng * 16 + lr;
            ushort4 o;
            o.x = f2b(frelu(z1a[mg][ng][0] + bb.x));
            o.y = f2b(frelu(z1a[mg][ng][1] + bb.y));
            o.z = f2b(frelu(z1a[mg][ng][2] + bb.z));
            o.w = f2b(frelu(z1a[mg][ng][3] + bb.w));
            *(ushort4*)&zl[sw256(n, m0)] = o;
        }
    }
    __syncthreads();

    // ---- R2: h = relu(h' + z @ W2 + b2); wave computes rows wid*16..+16 ----
    f32x4 r2[4];
#pragma unroll
    for (int mg = 0; mg < 4; ++mg) r2[mg] = (f32x4){0.f, 0.f, 0.f, 0.f};
#pragma unroll
    for (int kc = 0; kc < 256; kc += 32) {
        bf16x8 bz = *(const bf16x8*)&zl[sw256(wid * 16 + lr, kc + lkq * 8)];
#pragma unroll
        for (int mg = 0; mg < 4; ++mg) {
            bf16x8 a = *(const bf16x8*)(W2t + (size_t)(mg * 16 + lr) * 256 + kc + lkq * 8);
            r2[mg] = __builtin_amdgcn_mfma_f32_16x16x32_bf16(a, bz, r2[mg], 0, 0, 0);
        }
    }
    {
        int n = wid * 16 + lr;
#pragma unroll
        for (int mg = 0; mg < 4; ++mg) {
            int m0 = mg * 16 + lkq * 4;
            float4 bb = *(const float4*)(b2 + m0);
            ushort4 rs = *(const ushort4*)&tl[sw64(n, m0)];
            ushort4 o;
            o.x = f2b(frelu(r2[mg][0] + bb.x + b2f(rs.x)));
            o.y = f2b(frelu(r2[mg][1] + bb.y + b2f(rs.y)));
            o.z = f2b(frelu(r2[mg][2] + bb.z + b2f(rs.z)));
            o.w = f2b(frelu(r2[mg][3] + bb.w + b2f(rs.w)));
            *(ushort4*)(hout + (size_t)(rowBase + n) * 64 + m0) = o;
        }
    }
}

// ---------------- fused head: out = sig(relu(relu(hall@W1)@W2)@W3) ----------
__global__ __launch_bounds__(256) void k_head(const unsigned short* __restrict__ hb,   // [NB][512]
                                              const unsigned short* __restrict__ W1t,  // [256][512]
                                              const float* __restrict__ b1,
                                              const unsigned short* __restrict__ W2t,  // [128][256]
                                              const float* __restrict__ b2,
                                              const unsigned short* __restrict__ W3t,  // [9][128]
                                              const float* __restrict__ b3,
                                              float* __restrict__ out) {
    __shared__ unsigned short z1[64][280];
    __shared__ unsigned short z2[64][152];
    const int tid = threadIdx.x, wid = tid >> 6, l = tid & 63;
    const int lr = l & 15, lkq = l >> 4;
    const unsigned short* hall = hb + (size_t)blockIdx.x * 64 * 512;

    // GEMM1: z1[n][m], m in wid*64..+64, n all 64, K=512
    f32x4 acc1[4][4];
#pragma unroll
    for (int mg = 0; mg < 4; ++mg)
#pragma unroll
        for (int ng = 0; ng < 4; ++ng) acc1[mg][ng] = (f32x4){0.f, 0.f, 0.f, 0.f};

    for (int kc = 0; kc < 512; kc += 32) {
        bf16x8 bfr[4];
#pragma unroll
        for (int ng = 0; ng < 4; ++ng)
            bfr[ng] = *(const bf16x8*)(hall + (size_t)(ng * 16 + lr) * 512 + kc + lkq * 8);
#pragma unroll
        for (int mg = 0; mg < 4; ++mg) {
            bf16x8 a = *(const bf16x8*)(W1t + (size_t)(wid * 64 + mg * 16 + lr) * 512 + kc + lkq * 8);
#pragma unroll
            for (int ng = 0; ng < 4; ++ng)
                acc1[mg][ng] = __builtin_amdgcn_mfma_f32_16x16x32_bf16(a, bfr[ng], acc1[mg][ng], 0, 0, 0);
        }
    }
#pragma unroll
    for (int mg = 0; mg < 4; ++mg) {
        int m0 = wid * 64 + mg * 16 + lkq * 4;
        float4 bb = *(const float4*)(b1 + m0);
#pragma unroll
        for (int ng = 0; ng < 4; ++ng) {
            int n = ng * 16 + lr;
            ushort4 o;
            o.x = f2b(frelu(acc1[mg][ng][0] + bb.x));
            o.y = f2b(frelu(acc1[mg][ng][1] + bb.y));
            o.z = f2b(frelu(acc1[mg][ng][2] + bb.z));
            o.w = f2b(frelu(acc1[mg][ng][3] + bb.w));
            *(ushort4*)&z1[n][m0] = o;
        }
    }
    __syncthreads();

    // GEMM2: z2[n][m], m in wid*32..+32, n all 64, K=256
    f32x4 acc2[2][4];
#pragma unroll
    for (int mg = 0; mg < 2; ++mg)
#pragma unroll
        for (int ng = 0; ng < 4; ++ng) acc2[mg][ng] = (f32x4){0.f, 0.f, 0.f, 0.f};
#pragma unroll
    for (int kc = 0; kc < 256; kc += 32) {
        bf16x8 bfr[4];
#pragma unroll
        for (int ng = 0; ng < 4; ++ng)
            bfr[ng] = *(const bf16x8*)&z1[ng * 16 + lr][kc + lkq * 8];
#pragma unroll
        for (int mg = 0; mg < 2; ++mg) {
            bf16x8 a = *(const bf16x8*)(W2t + (size_t)(wid * 32 + mg * 16 + lr) * 256 + kc + lkq * 8);
#pragma unroll
            for (int ng = 0; ng < 4; ++ng)
                acc2[mg][ng] = __builtin_amdgcn_mfma_f32_16x16x32_bf16(a, bfr[ng], acc2[mg][ng], 0, 0, 0);
        }
    }
#pragma unroll
    for (int mg = 0; mg < 2; ++mg) {
        int m0 = wid * 32 + mg * 16 + lkq * 4;
        float4 bb = *(const float4*)(b2 + m0);
#pragma unroll
        for (int ng = 0; ng < 4; ++ng) {
            int n = ng * 16 + lr;
            ushort4 o;
            o.x = f2b(frelu(acc2[mg][ng][0] + bb.x));
            o.y = f2b(frelu(acc2[mg][ng][1] + bb.y));
            o.z = f2b(frelu(acc2[mg][ng][2] + bb.z));
            o.w = f2b(frelu(acc2[mg][ng][3] + bb.w));
            *(ushort4*)&z2[n][m0] = o;
        }
    }
    __syncthreads();

    // GEMM3: out[n][m<9], wave owns n = wid*16..+16, K=128
    f32x4 acc3 = (f32x4){0.f, 0.f, 0.f, 0.f};
    int arow = lr < 9 ? lr : 8;
#pragma unroll
    for (int kc = 0; kc < 128; kc += 32) {
        bf16x8 bz = *(const bf16x8*)&z2[wid * 16 + lr][kc + lkq * 8];
        bf16x8 a = *(const bf16x8*)(W3t + (size_t)arow * 128 + kc + lkq * 8);
        acc3 = __builtin_amdgcn_mfma_f32_16x16x32_bf16(a, bz, acc3, 0, 0, 0);
    }
    {
        long shot = (long)blockIdx.x * 64 + wid * 16 + lr;
#pragma unroll
        for (int r = 0; r < 4; ++r) {
            int m = lkq * 4 + r;
            if (m < 9) {
                float v = acc3[r] + b3[m];
                out[shot * 9 + m] = 1.f / (1.f + expf(-v));
            }
        }
    }
}

// ---------------- launcher ----------------
// Workspace (~144 MB): h0 67MB | h1 67MB | srcs 8.4MB | rowptr/cnt/bsum/dinv | Wt 1.2MB

extern "C" void kernel_launch(void* const* d_in, const int* in_sizes, int n_in,
                              void* d_out, int out_size, void* d_ws, size_t ws_size,
                              hipStream_t stream) {
    const float* syn  = (const float*)d_in[0];
    const int*   eidx = (const int*)d_in[1];
    const float* embW = (const float*)d_in[3];
    const float* embB = (const float*)d_in[4];
    const float* gcnW = (const float*)d_in[5];
    const float* gcnB = (const float*)d_in[6];
    const float* rW1  = (const float*)d_in[7];
    const float* rB1  = (const float*)d_in[8];
    const float* rW2  = (const float*)d_in[9];
    const float* rB2  = (const float*)d_in[10];
    const float* hW1  = (const float*)d_in[11];
    const float* hB1  = (const float*)d_in[12];
    const float* hW2  = (const float*)d_in[13];
    const float* hB2  = (const float*)d_in[14];
    const float* hW3  = (const float*)d_in[15];
    const float* hB3  = (const float*)d_in[16];
    float* out = (float*)d_out;

    unsigned short* h0     = (unsigned short*)d_ws;
    unsigned short* h1     = h0 + (size_t)NN * 64;
    int*            srcs   = (int*)(h1 + (size_t)NN * 64);
    int*            rowptr = srcs + NEDGE;
    int*            cnt    = rowptr + NN + 256;
    int*            bsum   = cnt + NN;
    float*          dinv   = (float*)(bsum + 512);
    unsigned short* gcnWt  = (unsigned short*)(dinv + NN);
    unsigned short* rW1t   = gcnWt + 3 * 64 * 64;
    unsigned short* rW2t   = rW1t + 3 * 64 * 256;
    unsigned short* hW1t   = rW2t + 3 * 256 * 64;
    unsigned short* hW2t   = hW1t + 3 * 512 * 256;
    unsigned short* hW3t   = hW2t + 3 * 256 * 128;

    // weight transposes (fp32 [K][M] -> bf16 [M][K], x3 iters each)
    k_trans<<<(3*64*64   + 255)/256, 256, 0, stream>>>(gcnW, gcnWt, 64, 64,  3*64*64);
    k_trans<<<(3*64*256  + 255)/256, 256, 0, stream>>>(rW1,  rW1t,  64, 256, 3*64*256);
    k_trans<<<(3*256*64  + 255)/256, 256, 0, stream>>>(rW2,  rW2t,  256, 64, 3*256*64);
    k_trans<<<(3*512*256 + 255)/256, 256, 0, stream>>>(hW1,  hW1t,  512, 256, 3*512*256);
    k_trans<<<(3*256*128 + 255)/256, 256, 0, stream>>>(hW2,  hW2t,  256, 128, 3*256*128);
    k_trans<<<(3*128*9   + 255)/256, 256, 0, stream>>>(hW3,  hW3t,  128, 9,   3*128*9);

    // CSR build
    k_cnt_init<<<NN / 256, 256, 0, stream>>>(cnt);
    k_hist<<<NEDGE / 256, 256, 0, stream>>>(eidx, cnt);
    k_scan1<<<512, 256, 0, stream>>>(cnt, rowptr, bsum, dinv);
    k_scan2<<<1, 512, 0, stream>>>(bsum);
    k_scan3<<<512, 256, 0, stream>>>(rowptr, bsum, cnt);
    k_fill<<<NEDGE / 256, 256, 0, stream>>>(eidx, cnt, srcs);

    unsigned short* hcur = h0;
    unsigned short* hnxt = h1;
    for (int i = 0; i < NITERS; ++i) {
        unsigned short* hdst = (i == 0) ? h0 : hnxt;
        if (i == 0) {
            k_gcnref<true><<<NN / 64, 256, 0, stream>>>(
                rowptr, srcs, dinv, syn, embW, embB, nullptr,
                gcnWt, gcnB,
                rW1t, rB1, rW2t, rB2, h0);
        } else {
            k_gcnref<false><<<NN / 64, 256, 0, stream>>>(
                rowptr, srcs, dinv, nullptr, nullptr, nullptr, hcur,
                gcnWt + (size_t)i * 64 * 64, gcnB + (size_t)i * 64,
                rW1t + (size_t)i * 64 * 256, rB1 + (size_t)i * 256,
                rW2t + (size_t)i * 256 * 64, rB2 + (size_t)i * 64, hdst);
        }
        k_head<<<NB / 64, 256, 0, stream>>>(hdst,
                                            hW1t + (size_t)i * 512 * 256, hB1 + (size_t)i * 256,
                                            hW2t + (size_t)i * 256 * 128, hB2 + (size_t)i * 128,
                                            hW3t + (size_t)i * 128 * 9,   hB3 + (size_t)i * 9,
                                            out + (size_t)i * NB * NQ);
        if (i == 0) { hcur = h0; hnxt = h1; }
        else { unsigned short* t = hcur; hcur = hdst; hnxt = t; }
    }
}

// Round 7
// 1312.285 us; speedup vs baseline: 20.2660x; 1.0375x over previous
//
#include <hip/hip_runtime.h>
#include <cstdint>

#define NN 524288       // total nodes = B*S
#define NB 65536        // batch
#define NQ 9
#define NEDGE 2097152
#define NITERS 3

typedef __attribute__((ext_vector_type(8))) short bf16x8;
typedef __attribute__((ext_vector_type(4))) float f32x4;

// ---------------- bf16 helpers (bit-level, RNE) ----------------
__device__ __forceinline__ unsigned short f2b(float f) {
    union { float f; unsigned u; } v; v.f = f;
    unsigned u = v.u;
    u += 0x7FFFu + ((u >> 16) & 1u);
    return (unsigned short)(u >> 16);
}
__device__ __forceinline__ float b2f(unsigned short b) {
    union { unsigned u; float f; } v; v.u = ((unsigned)b) << 16;
    return v.f;
}
__device__ __forceinline__ float frelu(float v) { return v > 0.f ? v : 0.f; }

// Swizzled LDS index (ushort units): XOR row&7 into ushort-col bits 3..5.
// Makes 16-rows-at-same-column ds_read_b128 conflict-light.
__device__ __forceinline__ int sw64(int r, int c)  { return r * 64  + (c ^ ((r & 7) << 3)); }
__device__ __forceinline__ int sw128(int r, int c) { return r * 128 + (c ^ ((r & 7) << 3)); }

// ---------------- CSR construction ----------------

__global__ void k_cnt_init(int* __restrict__ cnt) {
    cnt[blockIdx.x * 256 + threadIdx.x] = 0;
}

__global__ void k_hist(const int* __restrict__ eidx, int* __restrict__ cnt) {
    int e = blockIdx.x * 256 + threadIdx.x;
    atomicAdd(&cnt[eidx[NEDGE + e]], 1);
}

__global__ void k_scan1(const int* __restrict__ cnt, int* __restrict__ rowptr,
                        int* __restrict__ bsum, float* __restrict__ dinv) {
    __shared__ int sd[256];
    int tid = threadIdx.x;
    int base = (blockIdx.x * 256 + tid) * 4;
    int c0 = cnt[base], c1 = cnt[base + 1], c2 = cnt[base + 2], c3 = cnt[base + 3];
    dinv[base]     = rsqrtf(1.f + (float)c0);
    dinv[base + 1] = rsqrtf(1.f + (float)c1);
    dinv[base + 2] = rsqrtf(1.f + (float)c2);
    dinv[base + 3] = rsqrtf(1.f + (float)c3);
    int t = c0 + c1 + c2 + c3;
    sd[tid] = t; __syncthreads();
    for (int o = 1; o < 256; o <<= 1) {
        int v = (tid >= o) ? sd[tid - o] : 0;
        __syncthreads();
        sd[tid] += v;
        __syncthreads();
    }
    int excl = sd[tid] - t;
    rowptr[base]     = excl;
    rowptr[base + 1] = excl + c0;
    rowptr[base + 2] = excl + c0 + c1;
    rowptr[base + 3] = excl + c0 + c1 + c2;
    if (tid == 255) bsum[blockIdx.x] = sd[255];
}

__global__ void k_scan2(int* __restrict__ bsum) {   // 1 block x 512
    __shared__ int sd[512];
    int tid = threadIdx.x;
    int v = bsum[tid];
    sd[tid] = v; __syncthreads();
    for (int o = 1; o < 512; o <<= 1) {
        int u = (tid >= o) ? sd[tid - o] : 0;
        __syncthreads();
        sd[tid] += u;
        __syncthreads();
    }
    bsum[tid] = sd[tid] - v;   // exclusive
}

__global__ void k_scan3(int* __restrict__ rowptr, const int* __restrict__ bsum,
                        int* __restrict__ cursor) {
    int tid = threadIdx.x;
    int base = (blockIdx.x * 256 + tid) * 4;
    int off = bsum[blockIdx.x];
#pragma unroll
    for (int j = 0; j < 4; ++j) {
        int r = rowptr[base + j] + off;
        rowptr[base + j] = r;
        cursor[base + j] = r;
    }
    if (blockIdx.x == 511 && tid == 255) rowptr[NN] = NEDGE;
}

__global__ void k_fill(const int* __restrict__ eidx, int* __restrict__ cursor,
                       int* __restrict__ srcs) {
    int e = blockIdx.x * 256 + threadIdx.x;
    int s = eidx[e], d = eidx[NEDGE + e];
    int pos = atomicAdd(&cursor[d], 1);
    srcs[pos] = s;
}

// ---------------- weight transpose W[K][M] fp32 -> Wt[M][K] bf16 (x3 iters) ----
__global__ void k_trans(const float* __restrict__ W, unsigned short* __restrict__ Wt,
                        int K, int M, int total) {
    int o = blockIdx.x * 256 + threadIdx.x;
    if (o >= total) return;
    int km = K * M;
    int it = o / km;
    int rem = o - it * km;
    int m = rem / K;
    int k = rem - m * K;
    Wt[o] = f2b(W[(size_t)it * km + (size_t)k * M + m]);
}

// =====================================================================
// Swapped MFMA orientation: A = weights (m = out-col), B = activations
// (n = out-row).  A-frag: Wt[m=base+l&15][kc+(l>>4)*8..+8] row-contig.
// B-frag: act[n=base+l&15][kc+(l>>4)*8..+8] row-contig.
// C: lane holds m=(l>>4)*4+r (4 consecutive out-cols), n=l&15.
// =====================================================================

// ---------------- fused gather + GCN + refine (+ embed for iter 0) --------
// Block = 64 nodes.  LDS: tl 8KB (agg/h' tile) + zl 16KB (z half-tile) = 24KB
// -> 6 blocks/CU.  Gather: 8 row-loads in flight per wave (unroll-2 over 4
// nodes).  Refine z computed in two 128-col halves, R2 accumulates across.

template<bool EMBED>
__global__ __launch_bounds__(256, 6) void k_gcnref(
    const int* __restrict__ rowptr, const int* __restrict__ srcs,
    const float* __restrict__ dinv,
    const float* __restrict__ syn, const float* __restrict__ embW,
    const float* __restrict__ embB,
    const unsigned short* __restrict__ hin,
    const unsigned short* __restrict__ Wgt, const float* __restrict__ bg,
    const unsigned short* __restrict__ W1t, const float* __restrict__ b1,
    const unsigned short* __restrict__ W2t, const float* __restrict__ b2,
    unsigned short* __restrict__ hout)
{
    __shared__ unsigned short tl[64 * 64];    // agg tile, then h' tile (swizzled)
    __shared__ unsigned short zl[64 * 128];   // z half-tile (swizzled)
    const int tid = threadIdx.x, wid = tid >> 6, l = tid & 63;
    const int lr = l & 15, lkq = l >> 4;
    const int rowBase = blockIdx.x * 64;

    float ew = 0.f, ebv = 0.f;
    if (EMBED) { ew = embW[l]; ebv = embB[l]; }

    // ---- gather: wave owns rows wid*16..+16; 4 nodes per g-group ----
    const int nb = rowBase + wid * 16;
    for (int g = 0; g < 4; ++g) {
        const int jn = nb + g * 4 + lkq;          // node this lane preloads for
        int beg = rowptr[jn];
        int dgl = rowptr[jn + 1] - beg;
        int   sl = (lr < dgl) ? srcs[beg + lr] : jn;   // pad: self, weight 0
        float wl = (lr < dgl) ? dinv[sl] : 0.f;

        int n0 = nb + g * 4;
        float d0 = dinv[n0], d1 = dinv[n0 + 1], d2 = dinv[n0 + 2], d3 = dinv[n0 + 3];
        float a0, a1, a2, a3;
        if (EMBED) {
            a0 = (syn[n0] * ew + ebv) * d0;
            a1 = (syn[n0 + 1] * ew + ebv) * d1;
            a2 = (syn[n0 + 2] * ew + ebv) * d2;
            a3 = (syn[n0 + 3] * ew + ebv) * d3;
        } else {
            a0 = b2f(hin[(size_t)n0 * 64 + l]) * d0;
            a1 = b2f(hin[(size_t)(n0 + 1) * 64 + l]) * d1;
            a2 = b2f(hin[(size_t)(n0 + 2) * 64 + l]) * d2;
            a3 = b2f(hin[(size_t)(n0 + 3) * 64 + l]) * d3;
        }
        int dg0 = __shfl(dgl, 0), dg1 = __shfl(dgl, 16);
        int dg2 = __shfl(dgl, 32), dg3 = __shfl(dgl, 48);
        int dmax = max(max(dg0, dg1), max(dg2, dg3));
        int dfast = dmax < 16 ? dmax : 16;

        // unroll-2: 8 independent row loads in flight
        int p = 0;
        for (; p + 1 < dfast; p += 2) {
            int s00 = __shfl(sl, p),      s01 = __shfl(sl, 16 + p);
            int s02 = __shfl(sl, 32 + p), s03 = __shfl(sl, 48 + p);
            int s10 = __shfl(sl, p + 1),      s11 = __shfl(sl, 17 + p);
            int s12 = __shfl(sl, 33 + p), s13 = __shfl(sl, 49 + p);
            float w00 = __shfl(wl, p),      w01 = __shfl(wl, 16 + p);
            float w02 = __shfl(wl, 32 + p), w03 = __shfl(wl, 48 + p);
            float w10 = __shfl(wl, p + 1),      w11 = __shfl(wl, 17 + p);
            float w12 = __shfl(wl, 33 + p), w13 = __shfl(wl, 49 + p);
            float v00, v01, v02, v03, v10, v11, v12, v13;
            if (EMBED) {
                v00 = syn[s00] * ew + ebv; v01 = syn[s01] * ew + ebv;
                v02 = syn[s02] * ew + ebv; v03 = syn[s03] * ew + ebv;
                v10 = syn[s10] * ew + ebv; v11 = syn[s11] * ew + ebv;
                v12 = syn[s12] * ew + ebv; v13 = syn[s13] * ew + ebv;
            } else {
                v00 = b2f(hin[(size_t)s00 * 64 + l]);
                v01 = b2f(hin[(size_t)s01 * 64 + l]);
                v02 = b2f(hin[(size_t)s02 * 64 + l]);
                v03 = b2f(hin[(size_t)s03 * 64 + l]);
                v10 = b2f(hin[(size_t)s10 * 64 + l]);
                v11 = b2f(hin[(size_t)s11 * 64 + l]);
                v12 = b2f(hin[(size_t)s12 * 64 + l]);
                v13 = b2f(hin[(size_t)s13 * 64 + l]);
            }
            a0 += v00 * w00; a1 += v01 * w01; a2 += v02 * w02; a3 += v03 * w03;
            a0 += v10 * w10; a1 += v11 * w11; a2 += v12 * w12; a3 += v13 * w13;
        }
        if (p < dfast) {
            int s00 = __shfl(sl, p),      s01 = __shfl(sl, 16 + p);
            int s02 = __shfl(sl, 32 + p), s03 = __shfl(sl, 48 + p);
            float w00 = __shfl(wl, p),      w01 = __shfl(wl, 16 + p);
            float w02 = __shfl(wl, 32 + p), w03 = __shfl(wl, 48 + p);
            float v00, v01, v02, v03;
            if (EMBED) {
                v00 = syn[s00] * ew + ebv; v01 = syn[s01] * ew + ebv;
                v02 = syn[s02] * ew + ebv; v03 = syn[s03] * ew + ebv;
            } else {
                v00 = b2f(hin[(size_t)s00 * 64 + l]);
                v01 = b2f(hin[(size_t)s01 * 64 + l]);
                v02 = b2f(hin[(size_t)s02 * 64 + l]);
                v03 = b2f(hin[(size_t)s03 * 64 + l]);
            }
            a0 += v00 * w00; a1 += v01 * w01; a2 += v02 * w02; a3 += v03 * w03;
        }
        if (dmax > 16) {                           // vanishingly rare tail
            int b0 = __shfl(beg, 0), b1_ = __shfl(beg, 16);
            int b2_ = __shfl(beg, 32), b3_ = __shfl(beg, 48);
            for (int q = 16; q < dg0; ++q) { int s = srcs[b0 + q];
                a0 += (EMBED ? syn[s] * ew + ebv : b2f(hin[(size_t)s * 64 + l])) * dinv[s]; }
            for (int q = 16; q < dg1; ++q) { int s = srcs[b1_ + q];
                a1 += (EMBED ? syn[s] * ew + ebv : b2f(hin[(size_t)s * 64 + l])) * dinv[s]; }
            for (int q = 16; q < dg2; ++q) { int s = srcs[b2_ + q];
                a2 += (EMBED ? syn[s] * ew + ebv : b2f(hin[(size_t)s * 64 + l])) * dinv[s]; }
            for (int q = 16; q < dg3; ++q) { int s = srcs[b3_ + q];
                a3 += (EMBED ? syn[s] * ew + ebv : b2f(hin[(size_t)s * 64 + l])) * dinv[s]; }
        }
        tl[sw64(wid * 16 + g * 4 + 0, l)] = f2b(a0 * d0);
        tl[sw64(wid * 16 + g * 4 + 1, l)] = f2b(a1 * d1);
        tl[sw64(wid * 16 + g * 4 + 2, l)] = f2b(a2 * d2);
        tl[sw64(wid * 16 + g * 4 + 3, l)] = f2b(a3 * d3);
    }
    __syncthreads();

    // ---- GCN: h' = relu(agg @ Wg + bg); wave reads/writes ONLY its own
    //      16 rows of tl, so no barrier needed between read and overwrite ----
    f32x4 ag[4];
#pragma unroll
    for (int mg = 0; mg < 4; ++mg) ag[mg] = (f32x4){0.f, 0.f, 0.f, 0.f};
#pragma unroll
    for (int kc = 0; kc < 64; kc += 32) {
        bf16x8 bfr = *(const bf16x8*)&tl[sw64(wid * 16 + lr, kc + lkq * 8)];
#pragma unroll
        for (int mg = 0; mg < 4; ++mg) {
            bf16x8 a = *(const bf16x8*)(Wgt + (size_t)(mg * 16 + lr) * 64 + kc + lkq * 8);
            ag[mg] = __builtin_amdgcn_mfma_f32_16x16x32_bf16(a, bfr, ag[mg], 0, 0, 0);
        }
    }
#pragma unroll
    for (int mg = 0; mg < 4; ++mg) {
        int m0 = mg * 16 + lkq * 4;
        float4 bb = *(const float4*)(bg + m0);
        ushort4 o;
        o.x = f2b(frelu(ag[mg][0] + bb.x));
        o.y = f2b(frelu(ag[mg][1] + bb.y));
        o.z = f2b(frelu(ag[mg][2] + bb.z));
        o.w = f2b(frelu(ag[mg][3] + bb.w));
        *(ushort4*)&tl[sw64(wid * 16 + lr, m0)] = o;   // overwrite own rows with h'
    }
    __syncthreads();

    // ---- refine in two 128-col halves; r2 accumulates across halves ----
    f32x4 r2[4];
#pragma unroll
    for (int mg = 0; mg < 4; ++mg) r2[mg] = (f32x4){0.f, 0.f, 0.f, 0.f};

#pragma unroll
    for (int half = 0; half < 2; ++half) {
        // R1 half: z[:, half*128 + (0..127)] = relu(h' @ W1half + b1half)
        f32x4 z1a[2][4];
#pragma unroll
        for (int mg = 0; mg < 2; ++mg)
#pragma unroll
            for (int ng = 0; ng < 4; ++ng) z1a[mg][ng] = (f32x4){0.f, 0.f, 0.f, 0.f};
#pragma unroll
        for (int kc = 0; kc < 64; kc += 32) {
            bf16x8 bfr[4];
#pragma unroll
            for (int ng = 0; ng < 4; ++ng)
                bfr[ng] = *(const bf16x8*)&tl[sw64(ng * 16 + lr, kc + lkq * 8)];
#pragma unroll
            for (int mg = 0; mg < 2; ++mg) {
                bf16x8 a = *(const bf16x8*)(W1t +
                    (size_t)(half * 128 + wid * 32 + mg * 16 + lr) * 64 + kc + lkq * 8);
#pragma unroll
                for (int ng = 0; ng < 4; ++ng)
                    z1a[mg][ng] = __builtin_amdgcn_mfma_f32_16x16x32_bf16(a, bfr[ng], z1a[mg][ng], 0, 0, 0);
            }
        }
#pragma unroll
        for (int mg = 0; mg < 2; ++mg) {
            int m0 = wid * 32 + mg * 16 + lkq * 4;        // local col within half
            float4 bb = *(const float4*)(b1 + half * 128 + m0);
#pragma unroll
            for (int ng = 0; ng < 4; ++ng) {
                int n = ng * 16 + lr;
                ushort4 o;
                o.x = f2b(frelu(z1a[mg][ng][0] + bb.x));
                o.y = f2b(frelu(z1a[mg][ng][1] + bb.y));
                o.z = f2b(frelu(z1a[mg][ng][2] + bb.z));
                o.w = f2b(frelu(z1a[mg][ng][3] + bb.w));
                *(ushort4*)&zl[sw128(n, m0)] = o;
            }
        }
        __syncthreads();

        // R2 partial: accumulate k = half*128 .. +128
#pragma unroll
        for (int kc = 0; kc < 128; kc += 32) {
            bf16x8 bz = *(const bf16x8*)&zl[sw128(wid * 16 + lr, kc + lkq * 8)];
#pragma unroll
            for (int mg = 0; mg < 4; ++mg) {
                bf16x8 a = *(const bf16x8*)(W2t +
                    (size_t)(mg * 16 + lr) * 256 + half * 128 + kc + lkq * 8);
                r2[mg] = __builtin_amdgcn_mfma_f32_16x16x32_bf16(a, bz, r2[mg], 0, 0, 0);
            }
        }
        if (half == 0) __syncthreads();   // before next half overwrites zl
    }

    // ---- epilogue: h = relu(h' + r + b2) ----
    {
        int n = wid * 16 + lr;
#pragma unroll
        for (int mg = 0; mg < 4; ++mg) {
            int m0 = mg * 16 + lkq * 4;
            float4 bb = *(const float4*)(b2 + m0);
            ushort4 rs = *(const ushort4*)&tl[sw64(n, m0)];
            ushort4 o;
            o.x = f2b(frelu(r2[mg][0] + bb.x + b2f(rs.x)));
            o.y = f2b(frelu(r2[mg][1] + bb.y + b2f(rs.y)));
            o.z = f2b(frelu(r2[mg][2] + bb.z + b2f(rs.z)));
            o.w = f2b(frelu(r2[mg][3] + bb.w + b2f(rs.w)));
            *(ushort4*)(hout + (size_t)(rowBase + n) * 64 + m0) = o;
        }
    }
}

// ---------------- fused head: out = sig(relu(relu(hall@W1)@W2)@W3) ----------
__global__ __launch_bounds__(256) void k_head(const unsigned short* __restrict__ hb,   // [NB][512]
                                              const unsigned short* __restrict__ W1t,  // [256][512]
                                              const float* __restrict__ b1,
                                              const unsigned short* __restrict__ W2t,  // [128][256]
                                              const float* __restrict__ b2,
                                              const unsigned short* __restrict__ W3t,  // [9][128]
                                              const float* __restrict__ b3,
                                              float* __restrict__ out) {
    __shared__ unsigned short z1[64][280];
    __shared__ unsigned short z2[64][152];
    const int tid = threadIdx.x, wid = tid >> 6, l = tid & 63;
    const int lr = l & 15, lkq = l >> 4;
    const unsigned short* hall = hb + (size_t)blockIdx.x * 64 * 512;

    // GEMM1: z1[n][m], m in wid*64..+64, n all 64, K=512
    f32x4 acc1[4][4];
#pragma unroll
    for (int mg = 0; mg < 4; ++mg)
#pragma unroll
        for (int ng = 0; ng < 4; ++ng) acc1[mg][ng] = (f32x4){0.f, 0.f, 0.f, 0.f};

    for (int kc = 0; kc < 512; kc += 32) {
        bf16x8 bfr[4];
#pragma unroll
        for (int ng = 0; ng < 4; ++ng)
            bfr[ng] = *(const bf16x8*)(hall + (size_t)(ng * 16 + lr) * 512 + kc + lkq * 8);
#pragma unroll
        for (int mg = 0; mg < 4; ++mg) {
            bf16x8 a = *(const bf16x8*)(W1t + (size_t)(wid * 64 + mg * 16 + lr) * 512 + kc + lkq * 8);
#pragma unroll
            for (int ng = 0; ng < 4; ++ng)
                acc1[mg][ng] = __builtin_amdgcn_mfma_f32_16x16x32_bf16(a, bfr[ng], acc1[mg][ng], 0, 0, 0);
        }
    }
#pragma unroll
    for (int mg = 0; mg < 4; ++mg) {
        int m0 = wid * 64 + mg * 16 + lkq * 4;
        float4 bb = *(const float4*)(b1 + m0);
#pragma unroll
        for (int ng = 0; ng < 4; ++ng) {
            int n = ng * 16 + lr;
            ushort4 o;
            o.x = f2b(frelu(acc1[mg][ng][0] + bb.x));
            o.y = f2b(frelu(acc1[mg][ng][1] + bb.y));
            o.z = f2b(frelu(acc1[mg][ng][2] + bb.z));
            o.w = f2b(frelu(acc1[mg][ng][3] + bb.w));
            *(ushort4*)&z1[n][m0] = o;
        }
    }
    __syncthreads();

    // GEMM2: z2[n][m], m in wid*32..+32, n all 64, K=256
    f32x4 acc2[2][4];
#pragma unroll
    for (int mg = 0; mg < 2; ++mg)
#pragma unroll
        for (int ng = 0; ng < 4; ++ng) acc2[mg][ng] = (f32x4){0.f, 0.f, 0.f, 0.f};
#pragma unroll
    for (int kc = 0; kc < 256; kc += 32) {
        bf16x8 bfr[4];
#pragma unroll
        for (int ng = 0; ng < 4; ++ng)
            bfr[ng] = *(const bf16x8*)&z1[ng * 16 + lr][kc + lkq * 8];
#pragma unroll
        for (int mg = 0; mg < 2; ++mg) {
            bf16x8 a = *(const bf16x8*)(W2t + (size_t)(wid * 32 + mg * 16 + lr) * 256 + kc + lkq * 8);
#pragma unroll
            for (int ng = 0; ng < 4; ++ng)
                acc2[mg][ng] = __builtin_amdgcn_mfma_f32_16x16x32_bf16(a, bfr[ng], acc2[mg][ng], 0, 0, 0);
        }
    }
#pragma unroll
    for (int mg = 0; mg < 2; ++mg) {
        int m0 = wid * 32 + mg * 16 + lkq * 4;
        float4 bb = *(const float4*)(b2 + m0);
#pragma unroll
        for (int ng = 0; ng < 4; ++ng) {
            int n = ng * 16 + lr;
            ushort4 o;
            o.x = f2b(frelu(acc2[mg][ng][0] + bb.x));
            o.y = f2b(frelu(acc2[mg][ng][1] + bb.y));
            o.z = f2b(frelu(acc2[mg][ng][2] + bb.z));
            o.w = f2b(frelu(acc2[mg][ng][3] + bb.w));
            *(ushort4*)&z2[n][m0] = o;
        }
    }
    __syncthreads();

    // GEMM3: out[n][m<9], wave owns n = wid*16..+16, K=128
    f32x4 acc3 = (f32x4){0.f, 0.f, 0.f, 0.f};
    int arow = lr < 9 ? lr : 8;
#pragma unroll
    for (int kc = 0; kc < 128; kc += 32) {
        bf16x8 bz = *(const bf16x8*)&z2[wid * 16 + lr][kc + lkq * 8];
        bf16x8 a = *(const bf16x8*)(W3t + (size_t)arow * 128 + kc + lkq * 8);
        acc3 = __builtin_amdgcn_mfma_f32_16x16x32_bf16(a, bz, acc3, 0, 0, 0);
    }
    {
        long shot = (long)blockIdx.x * 64 + wid * 16 + lr;
#pragma unroll
        for (int r = 0; r < 4; ++r) {
            int m = lkq * 4 + r;
            if (m < 9) {
                float v = acc3[r] + b3[m];
                out[shot * 9 + m] = 1.f / (1.f + expf(-v));
            }
        }
    }
}

// ---------------- launcher ----------------
// Workspace (~144 MB): h0 67MB | h1 67MB | srcs 8.4MB | rowptr/cnt/bsum/dinv | Wt 1.2MB

extern "C" void kernel_launch(void* const* d_in, const int* in_sizes, int n_in,
                              void* d_out, int out_size, void* d_ws, size_t ws_size,
                              hipStream_t stream) {
    const float* syn  = (const float*)d_in[0];
    const int*   eidx = (const int*)d_in[1];
    const float* embW = (const float*)d_in[3];
    const float* embB = (const float*)d_in[4];
    const float* gcnW = (const float*)d_in[5];
    const float* gcnB = (const float*)d_in[6];
    const float* rW1  = (const float*)d_in[7];
    const float* rB1  = (const float*)d_in[8];
    const float* rW2  = (const float*)d_in[9];
    const float* rB2  = (const float*)d_in[10];
    const float* hW1  = (const float*)d_in[11];
    const float* hB1  = (const float*)d_in[12];
    const float* hW2  = (const float*)d_in[13];
    const float* hB2  = (const float*)d_in[14];
    const float* hW3  = (const float*)d_in[15];
    const float* hB3  = (const float*)d_in[16];
    float* out = (float*)d_out;

    unsigned short* h0     = (unsigned short*)d_ws;
    unsigned short* h1     = h0 + (size_t)NN * 64;
    int*            srcs   = (int*)(h1 + (size_t)NN * 64);
    int*            rowptr = srcs + NEDGE;
    int*            cnt    = rowptr + NN + 256;
    int*            bsum   = cnt + NN;
    float*          dinv   = (float*)(bsum + 512);
    unsigned short* gcnWt  = (unsigned short*)(dinv + NN);
    unsigned short* rW1t   = gcnWt + 3 * 64 * 64;
    unsigned short* rW2t   = rW1t + 3 * 64 * 256;
    unsigned short* hW1t   = rW2t + 3 * 256 * 64;
    unsigned short* hW2t   = hW1t + 3 * 512 * 256;
    unsigned short* hW3t   = hW2t + 3 * 256 * 128;

    // weight transposes (fp32 [K][M] -> bf16 [M][K], x3 iters each)
    k_trans<<<(3*64*64   + 255)/256, 256, 0, stream>>>(gcnW, gcnWt, 64, 64,  3*64*64);
    k_trans<<<(3*64*256  + 255)/256, 256, 0, stream>>>(rW1,  rW1t,  64, 256, 3*64*256);
    k_trans<<<(3*256*64  + 255)/256, 256, 0, stream>>>(rW2,  rW2t,  256, 64, 3*256*64);
    k_trans<<<(3*512*256 + 255)/256, 256, 0, stream>>>(hW1,  hW1t,  512, 256, 3*512*256);
    k_trans<<<(3*256*128 + 255)/256, 256, 0, stream>>>(hW2,  hW2t,  256, 128, 3*256*128);
    k_trans<<<(3*128*9   + 255)/256, 256, 0, stream>>>(hW3,  hW3t,  128, 9,   3*128*9);

    // CSR build
    k_cnt_init<<<NN / 256, 256, 0, stream>>>(cnt);
    k_hist<<<NEDGE / 256, 256, 0, stream>>>(eidx, cnt);
    k_scan1<<<512, 256, 0, stream>>>(cnt, rowptr, bsum, dinv);
    k_scan2<<<1, 512, 0, stream>>>(bsum);
    k_scan3<<<512, 256, 0, stream>>>(rowptr, bsum, cnt);
    k_fill<<<NEDGE / 256, 256, 0, stream>>>(eidx, cnt, srcs);

    unsigned short* hcur = h0;
    unsigned short* hnxt = h1;
    for (int i = 0; i < NITERS; ++i) {
        unsigned short* hdst = (i == 0) ? h0 : hnxt;
        if (i == 0) {
            k_gcnref<true><<<NN / 64, 256, 0, stream>>>(
                rowptr, srcs, dinv, syn, embW, embB, nullptr,
                gcnWt, gcnB,
                rW1t, rB1, rW2t, rB2, h0);
        } else {
            k_gcnref<false><<<NN / 64, 256, 0, stream>>>(
                rowptr, srcs, dinv, nullptr, nullptr, nullptr, hcur,
                gcnWt + (size_t)i * 64 * 64, gcnB + (size_t)i * 64,
                rW1t + (size_t)i * 64 * 256, rB1 + (size_t)i * 256,
                rW2t + (size_t)i * 256 * 64, rB2 + (size_t)i * 64, hdst);
        }
        k_head<<<NB / 64, 256, 0, stream>>>(hdst,
                                            hW1t + (size_t)i * 512 * 256, hB1 + (size_t)i * 256,
                                            hW2t + (size_t)i * 256 * 128, hB2 + (size_t)i * 128,
                                            hW3t + (size_t)i * 128 * 9,   hB3 + (size_t)i * 9,
                                            out + (size_t)i * NB * NQ);
        if (i == 0) { hcur = h0; hnxt = h1; }
        else { unsigned short* t = hcur; hcur = hdst; hnxt = t; }
    }
}

// Round 8
// 1236.917 us; speedup vs baseline: 21.5008x; 1.0609x over previous
//
#include <hip/hip_runtime.h>
#include <cstdint>

#define NN 524288       // total nodes = B*S
#define NB 65536        // batch
#define NQ 9
#define NEDGE 2097152
#define NITERS 3

typedef __attribute__((ext_vector_type(8))) short bf16x8;
typedef __attribute__((ext_vector_type(4))) float f32x4;

// ---------------- bf16 helpers (bit-level, RNE) ----------------
__device__ __forceinline__ unsigned short f2b(float f) {
    union { float f; unsigned u; } v; v.f = f;
    unsigned u = v.u;
    u += 0x7FFFu + ((u >> 16) & 1u);
    return (unsigned short)(u >> 16);
}
__device__ __forceinline__ float b2f(unsigned short b) {
    union { unsigned u; float f; } v; v.u = ((unsigned)b) << 16;
    return v.f;
}
__device__ __forceinline__ float frelu(float v) { return v > 0.f ? v : 0.f; }

// Swizzled LDS index (ushort units): XOR row&7 into ushort-col bits 3..5.
__device__ __forceinline__ int sw64(int r, int c)  { return r * 64  + (c ^ ((r & 7) << 3)); }

// ---------------- CSR construction ----------------

__global__ void k_cnt_init(int* __restrict__ cnt) {
    cnt[blockIdx.x * 256 + threadIdx.x] = 0;
}

__global__ void k_hist(const int* __restrict__ eidx, int* __restrict__ cnt) {
    int e = blockIdx.x * 256 + threadIdx.x;
    atomicAdd(&cnt[eidx[NEDGE + e]], 1);
}

__global__ void k_scan1(const int* __restrict__ cnt, int* __restrict__ rowptr,
                        int* __restrict__ bsum, float* __restrict__ dinv) {
    __shared__ int sd[256];
    int tid = threadIdx.x;
    int base = (blockIdx.x * 256 + tid) * 4;
    int c0 = cnt[base], c1 = cnt[base + 1], c2 = cnt[base + 2], c3 = cnt[base + 3];
    dinv[base]     = rsqrtf(1.f + (float)c0);
    dinv[base + 1] = rsqrtf(1.f + (float)c1);
    dinv[base + 2] = rsqrtf(1.f + (float)c2);
    dinv[base + 3] = rsqrtf(1.f + (float)c3);
    int t = c0 + c1 + c2 + c3;
    sd[tid] = t; __syncthreads();
    for (int o = 1; o < 256; o <<= 1) {
        int v = (tid >= o) ? sd[tid - o] : 0;
        __syncthreads();
        sd[tid] += v;
        __syncthreads();
    }
    int excl = sd[tid] - t;
    rowptr[base]     = excl;
    rowptr[base + 1] = excl + c0;
    rowptr[base + 2] = excl + c0 + c1;
    rowptr[base + 3] = excl + c0 + c1 + c2;
    if (tid == 255) bsum[blockIdx.x] = sd[255];
}

__global__ void k_scan2(int* __restrict__ bsum) {   // 1 block x 512
    __shared__ int sd[512];
    int tid = threadIdx.x;
    int v = bsum[tid];
    sd[tid] = v; __syncthreads();
    for (int o = 1; o < 512; o <<= 1) {
        int u = (tid >= o) ? sd[tid - o] : 0;
        __syncthreads();
        sd[tid] += u;
        __syncthreads();
    }
    bsum[tid] = sd[tid] - v;   // exclusive
}

__global__ void k_scan3(int* __restrict__ rowptr, const int* __restrict__ bsum,
                        int* __restrict__ cursor) {
    int tid = threadIdx.x;
    int base = (blockIdx.x * 256 + tid) * 4;
    int off = bsum[blockIdx.x];
#pragma unroll
    for (int j = 0; j < 4; ++j) {
        int r = rowptr[base + j] + off;
        rowptr[base + j] = r;
        cursor[base + j] = r;
    }
    if (blockIdx.x == 511 && tid == 255) rowptr[NN] = NEDGE;
}

__global__ void k_fill(const int* __restrict__ eidx, int* __restrict__ cursor,
                       int* __restrict__ srcs) {
    int e = blockIdx.x * 256 + threadIdx.x;
    int s = eidx[e], d = eidx[NEDGE + e];
    int pos = atomicAdd(&cursor[d], 1);
    srcs[pos] = s;
}

// ---------------- weight transpose W[K][M] fp32 -> Wt[M][K] bf16 (x3 iters) ----
__global__ void k_trans(const float* __restrict__ W, unsigned short* __restrict__ Wt,
                        int K, int M, int total) {
    int o = blockIdx.x * 256 + threadIdx.x;
    if (o >= total) return;
    int km = K * M;
    int it = o / km;
    int rem = o - it * km;
    int m = rem / K;
    int k = rem - m * K;
    Wt[o] = f2b(W[(size_t)it * km + (size_t)k * M + m]);
}

// =====================================================================
// Swapped MFMA orientation: A = weights (m = out-col), B = activations
// (n = out-row).  A-frag: Wt[m=base+l&15][kc+(l>>4)*8..+8] row-contig.
// B-frag: act[n=base+l&15][kc+(l>>4)*8..+8] row-contig.
// C: lane holds m=(l>>4)*4+r (4 consecutive out-cols), n=l&15.
// =====================================================================

// ---------------- fused gather + GCN + refine (+ embed for iter 0) --------
// Block = 64 nodes.  LDS: tl 8KB (agg/h' tile, then store-staging) +
// zl 8KB (z quarter-tile) = 16KB.
// Gather lane map: group g = l>>4 owns one node per quad; lane-in-group
// i = l&15 covers feats 4i..4i+3 (ushort4 = 8B; 16 lanes = one 128B row).
// One load instruction fetches 4 edges' rows; unroll-4 -> 16 lines in flight.

template<bool EMBED>
__global__ __launch_bounds__(256, 6) void k_gcnref(
    const int* __restrict__ rowptr, const int* __restrict__ srcs,
    const float* __restrict__ dinv,
    const float* __restrict__ syn, const float* __restrict__ embW,
    const float* __restrict__ embB,
    const unsigned short* __restrict__ hin,
    const unsigned short* __restrict__ Wgt, const float* __restrict__ bg,
    const unsigned short* __restrict__ W1t, const float* __restrict__ b1,
    const unsigned short* __restrict__ W2t, const float* __restrict__ b2,
    unsigned short* __restrict__ hout)
{
    __shared__ unsigned short tl[64 * 64];    // agg -> h' -> h_out staging
    __shared__ unsigned short zl[64 * 64];    // z quarter-tile
    const int tid = threadIdx.x, wid = tid >> 6, l = tid & 63;
    const int lr = l & 15, lkq = l >> 4;
    const int g = l >> 4, i = l & 15;         // gather roles
    const int rowBase = blockIdx.x * 64;
    const int nb = rowBase + wid * 16;

    float4 ew4, eb4;
    if (EMBED) {
        ew4 = *(const float4*)(embW + i * 4);
        eb4 = *(const float4*)(embB + i * 4);
    }

    // ---- gather: 4 quads of 4 nodes; group g owns node quad*4+g ----
    for (int q = 0; q < 4; ++q) {
        const int node = nb + q * 4 + g;
        int beg = rowptr[node];
        int deg = rowptr[node + 1] - beg;
        int   sl = (i < deg) ? srcs[beg + i] : node;   // pad: self, weight 0
        float wl = (i < deg) ? dinv[sl] : 0.f;

        float dn = dinv[node];
        float a0, a1, a2, a3;
        if (EMBED) {
            float s0 = syn[node];
            a0 = (s0 * ew4.x + eb4.x) * dn;
            a1 = (s0 * ew4.y + eb4.y) * dn;
            a2 = (s0 * ew4.z + eb4.z) * dn;
            a3 = (s0 * ew4.w + eb4.w) * dn;
        } else {
            ushort4 sv = *(const ushort4*)(hin + (size_t)node * 64 + i * 4);
            a0 = b2f(sv.x) * dn; a1 = b2f(sv.y) * dn;
            a2 = b2f(sv.z) * dn; a3 = b2f(sv.w) * dn;
        }

        int dmax = max(max(__shfl(deg, 0), __shfl(deg, 16)),
                       max(__shfl(deg, 32), __shfl(deg, 48)));
        int dfast = dmax < 16 ? dmax : 16;

        for (int p = 0; p < dfast; p += 4) {
            int   s[4]; float w[4];
#pragma unroll
            for (int u = 0; u < 4; ++u) {
                int pu = p + u;
                int idx = (l & 48) + (pu & 15);
                s[u] = __shfl(sl, idx);
                float wv = __shfl(wl, idx);
                w[u] = (pu < 16) ? wv : 0.f;
            }
            if (EMBED) {
                float sy[4];
#pragma unroll
                for (int u = 0; u < 4; ++u) sy[u] = syn[s[u]];
#pragma unroll
                for (int u = 0; u < 4; ++u) {
                    a0 += (sy[u] * ew4.x + eb4.x) * w[u];
                    a1 += (sy[u] * ew4.y + eb4.y) * w[u];
                    a2 += (sy[u] * ew4.z + eb4.z) * w[u];
                    a3 += (sy[u] * ew4.w + eb4.w) * w[u];
                }
            } else {
                ushort4 v[4];
#pragma unroll
                for (int u = 0; u < 4; ++u)
                    v[u] = *(const ushort4*)(hin + (size_t)s[u] * 64 + i * 4);
#pragma unroll
                for (int u = 0; u < 4; ++u) {
                    a0 += b2f(v[u].x) * w[u];
                    a1 += b2f(v[u].y) * w[u];
                    a2 += b2f(v[u].z) * w[u];
                    a3 += b2f(v[u].w) * w[u];
                }
            }
        }
        if (deg > 16) {                         // vanishingly rare tail (group-uniform)
            for (int t = 16; t < deg; ++t) {
                int st = srcs[beg + t];
                float wt = dinv[st];
                if (EMBED) {
                    float sy = syn[st];
                    a0 += (sy * ew4.x + eb4.x) * wt;
                    a1 += (sy * ew4.y + eb4.y) * wt;
                    a2 += (sy * ew4.z + eb4.z) * wt;
                    a3 += (sy * ew4.w + eb4.w) * wt;
                } else {
                    ushort4 v = *(const ushort4*)(hin + (size_t)st * 64 + i * 4);
                    a0 += b2f(v.x) * wt; a1 += b2f(v.y) * wt;
                    a2 += b2f(v.z) * wt; a3 += b2f(v.w) * wt;
                }
            }
        }
        ushort4 o;
        o.x = f2b(a0 * dn); o.y = f2b(a1 * dn);
        o.z = f2b(a2 * dn); o.w = f2b(a3 * dn);
        *(ushort4*)&tl[sw64(wid * 16 + q * 4 + g, i * 4)] = o;
    }
    // no barrier: GCN below reads only this wave's own 16 rows

    // ---- GCN: h' = relu(agg @ Wg + bg); wave computes its own 16 rows ----
    f32x4 ag[4];
#pragma unroll
    for (int mg = 0; mg < 4; ++mg) ag[mg] = (f32x4){0.f, 0.f, 0.f, 0.f};
#pragma unroll
    for (int kc = 0; kc < 64; kc += 32) {
        bf16x8 bfr = *(const bf16x8*)&tl[sw64(wid * 16 + lr, kc + lkq * 8)];
#pragma unroll
        for (int mg = 0; mg < 4; ++mg) {
            bf16x8 a = *(const bf16x8*)(Wgt + (size_t)(mg * 16 + lr) * 64 + kc + lkq * 8);
            ag[mg] = __builtin_amdgcn_mfma_f32_16x16x32_bf16(a, bfr, ag[mg], 0, 0, 0);
        }
    }
#pragma unroll
    for (int mg = 0; mg < 4; ++mg) {
        int m0 = mg * 16 + lkq * 4;
        float4 bb = *(const float4*)(bg + m0);
        ushort4 o;
        o.x = f2b(frelu(ag[mg][0] + bb.x));
        o.y = f2b(frelu(ag[mg][1] + bb.y));
        o.z = f2b(frelu(ag[mg][2] + bb.z));
        o.w = f2b(frelu(ag[mg][3] + bb.w));
        *(ushort4*)&tl[sw64(wid * 16 + lr, m0)] = o;   // overwrite own rows with h'
    }
    __syncthreads();

    // ---- refine in four 64-col quarters; r2 accumulates across quarters ----
    f32x4 r2[4];
#pragma unroll
    for (int mg = 0; mg < 4; ++mg) r2[mg] = (f32x4){0.f, 0.f, 0.f, 0.f};

#pragma unroll
    for (int qt = 0; qt < 4; ++qt) {
        // R1 quarter: z cols qt*64..+64; this wave computes 16 of them
        f32x4 z1a[4];
#pragma unroll
        for (int ng = 0; ng < 4; ++ng) z1a[ng] = (f32x4){0.f, 0.f, 0.f, 0.f};
#pragma unroll
        for (int kc = 0; kc < 64; kc += 32) {
            bf16x8 a = *(const bf16x8*)(W1t +
                (size_t)(qt * 64 + wid * 16 + lr) * 64 + kc + lkq * 8);
#pragma unroll
            for (int ng = 0; ng < 4; ++ng) {
                bf16x8 bfr = *(const bf16x8*)&tl[sw64(ng * 16 + lr, kc + lkq * 8)];
                z1a[ng] = __builtin_amdgcn_mfma_f32_16x16x32_bf16(a, bfr, z1a[ng], 0, 0, 0);
            }
        }
        {
            int m0 = wid * 16 + lkq * 4;                 // local col within quarter
            float4 bb = *(const float4*)(b1 + qt * 64 + m0);
#pragma unroll
            for (int ng = 0; ng < 4; ++ng) {
                int n = ng * 16 + lr;
                ushort4 o;
                o.x = f2b(frelu(z1a[ng][0] + bb.x));
                o.y = f2b(frelu(z1a[ng][1] + bb.y));
                o.z = f2b(frelu(z1a[ng][2] + bb.z));
                o.w = f2b(frelu(z1a[ng][3] + bb.w));
                *(ushort4*)&zl[sw64(n, m0)] = o;
            }
        }
        __syncthreads();

        // R2 partial: accumulate k = qt*64 .. +64
#pragma unroll
        for (int kc = 0; kc < 64; kc += 32) {
            bf16x8 bz = *(const bf16x8*)&zl[sw64(wid * 16 + lr, kc + lkq * 8)];
#pragma unroll
            for (int mg = 0; mg < 4; ++mg) {
                bf16x8 a = *(const bf16x8*)(W2t +
                    (size_t)(mg * 16 + lr) * 256 + qt * 64 + kc + lkq * 8);
                r2[mg] = __builtin_amdgcn_mfma_f32_16x16x32_bf16(a, bz, r2[mg], 0, 0, 0);
            }
        }
        if (qt < 3) __syncthreads();   // before next quarter overwrites zl
    }

    // ---- epilogue: h = relu(h' + r + b2) -> stage in tl, then full-line copy ----
    {
        int n = wid * 16 + lr;
#pragma unroll
        for (int mg = 0; mg < 4; ++mg) {
            int m0 = mg * 16 + lkq * 4;
            float4 bb = *(const float4*)(b2 + m0);
            ushort4 rs = *(const ushort4*)&tl[sw64(n, m0)];
            ushort4 o;
            o.x = f2b(frelu(r2[mg][0] + bb.x + b2f(rs.x)));
            o.y = f2b(frelu(r2[mg][1] + bb.y + b2f(rs.y)));
            o.z = f2b(frelu(r2[mg][2] + bb.z + b2f(rs.z)));
            o.w = f2b(frelu(r2[mg][3] + bb.w + b2f(rs.w)));
            *(ushort4*)&tl[sw64(n, m0)] = o;
        }
    }
    __syncthreads();
    {
        int r = tid >> 2, c16 = (tid & 3) * 16;     // 32 B per thread, full lines per 4 threads
        bf16x8 v0 = *(const bf16x8*)&tl[sw64(r, c16)];
        bf16x8 v1 = *(const bf16x8*)&tl[sw64(r, c16 + 8)];
        *(bf16x8*)(hout + (size_t)(rowBase + r) * 64 + c16) = v0;
        *(bf16x8*)(hout + (size_t)(rowBase + r) * 64 + c16 + 8) = v1;
    }
}

// ---------------- fused head: out = sig(relu(relu(hall@W1)@W2)@W3) ----------
__global__ __launch_bounds__(256) void k_head(const unsigned short* __restrict__ hb,   // [NB][512]
                                              const unsigned short* __restrict__ W1t,  // [256][512]
                                              const float* __restrict__ b1,
                                              const unsigned short* __restrict__ W2t,  // [128][256]
                                              const float* __restrict__ b2,
                                              const unsigned short* __restrict__ W3t,  // [9][128]
                                              const float* __restrict__ b3,
                                              float* __restrict__ out) {
    __shared__ unsigned short z1[64][280];
    __shared__ unsigned short z2[64][152];
    const int tid = threadIdx.x, wid = tid >> 6, l = tid & 63;
    const int lr = l & 15, lkq = l >> 4;
    const unsigned short* hall = hb + (size_t)blockIdx.x * 64 * 512;

    // GEMM1: z1[n][m], m in wid*64..+64, n all 64, K=512
    f32x4 acc1[4][4];
#pragma unroll
    for (int mg = 0; mg < 4; ++mg)
#pragma unroll
        for (int ng = 0; ng < 4; ++ng) acc1[mg][ng] = (f32x4){0.f, 0.f, 0.f, 0.f};

    for (int kc = 0; kc < 512; kc += 32) {
        bf16x8 bfr[4];
#pragma unroll
        for (int ng = 0; ng < 4; ++ng)
            bfr[ng] = *(const bf16x8*)(hall + (size_t)(ng * 16 + lr) * 512 + kc + lkq * 8);
#pragma unroll
        for (int mg = 0; mg < 4; ++mg) {
            bf16x8 a = *(const bf16x8*)(W1t + (size_t)(wid * 64 + mg * 16 + lr) * 512 + kc + lkq * 8);
#pragma unroll
            for (int ng = 0; ng < 4; ++ng)
                acc1[mg][ng] = __builtin_amdgcn_mfma_f32_16x16x32_bf16(a, bfr[ng], acc1[mg][ng], 0, 0, 0);
        }
    }
#pragma unroll
    for (int mg = 0; mg < 4; ++mg) {
        int m0 = wid * 64 + mg * 16 + lkq * 4;
        float4 bb = *(const float4*)(b1 + m0);
#pragma unroll
        for (int ng = 0; ng < 4; ++ng) {
            int n = ng * 16 + lr;
            ushort4 o;
            o.x = f2b(frelu(acc1[mg][ng][0] + bb.x));
            o.y = f2b(frelu(acc1[mg][ng][1] + bb.y));
            o.z = f2b(frelu(acc1[mg][ng][2] + bb.z));
            o.w = f2b(frelu(acc1[mg][ng][3] + bb.w));
            *(ushort4*)&z1[n][m0] = o;
        }
    }
    __syncthreads();

    // GEMM2: z2[n][m], m in wid*32..+32, n all 64, K=256
    f32x4 acc2[2][4];
#pragma unroll
    for (int mg = 0; mg < 2; ++mg)
#pragma unroll
        for (int ng = 0; ng < 4; ++ng) acc2[mg][ng] = (f32x4){0.f, 0.f, 0.f, 0.f};
#pragma unroll
    for (int kc = 0; kc < 256; kc += 32) {
        bf16x8 bfr[4];
#pragma unroll
        for (int ng = 0; ng < 4; ++ng)
            bfr[ng] = *(const bf16x8*)&z1[ng * 16 + lr][kc + lkq * 8];
#pragma unroll
        for (int mg = 0; mg < 2; ++mg) {
            bf16x8 a = *(const bf16x8*)(W2t + (size_t)(wid * 32 + mg * 16 + lr) * 256 + kc + lkq * 8);
#pragma unroll
            for (int ng = 0; ng < 4; ++ng)
                acc2[mg][ng] = __builtin_amdgcn_mfma_f32_16x16x32_bf16(a, bfr[ng], acc2[mg][ng], 0, 0, 0);
        }
    }
#pragma unroll
    for (int mg = 0; mg < 2; ++mg) {
        int m0 = wid * 32 + mg * 16 + lkq * 4;
        float4 bb = *(const float4*)(b2 + m0);
#pragma unroll
        for (int ng = 0; ng < 4; ++ng) {
            int n = ng * 16 + lr;
            ushort4 o;
            o.x = f2b(frelu(acc2[mg][ng][0] + bb.x));
            o.y = f2b(frelu(acc2[mg][ng][1] + bb.y));
            o.z = f2b(frelu(acc2[mg][ng][2] + bb.z));
            o.w = f2b(frelu(acc2[mg][ng][3] + bb.w));
            *(ushort4*)&z2[n][m0] = o;
        }
    }
    __syncthreads();

    // GEMM3: out[n][m<9], wave owns n = wid*16..+16, K=128
    f32x4 acc3 = (f32x4){0.f, 0.f, 0.f, 0.f};
    int arow = lr < 9 ? lr : 8;
#pragma unroll
    for (int kc = 0; kc < 128; kc += 32) {
        bf16x8 bz = *(const bf16x8*)&z2[wid * 16 + lr][kc + lkq * 8];
        bf16x8 a = *(const bf16x8*)(W3t + (size_t)arow * 128 + kc + lkq * 8);
        acc3 = __builtin_amdgcn_mfma_f32_16x16x32_bf16(a, bz, acc3, 0, 0, 0);
    }
    {
        long shot = (long)blockIdx.x * 64 + wid * 16 + lr;
#pragma unroll
        for (int r = 0; r < 4; ++r) {
            int m = lkq * 4 + r;
            if (m < 9) {
                float v = acc3[r] + b3[m];
                out[shot * 9 + m] = 1.f / (1.f + expf(-v));
            }
        }
    }
}

// ---------------- launcher ----------------
// Workspace (~144 MB): h0 67MB | h1 67MB | srcs 8.4MB | rowptr/cnt/bsum/dinv | Wt 1.2MB

extern "C" void kernel_launch(void* const* d_in, const int* in_sizes, int n_in,
                              void* d_out, int out_size, void* d_ws, size_t ws_size,
                              hipStream_t stream) {
    const float* syn  = (const float*)d_in[0];
    const int*   eidx = (const int*)d_in[1];
    const float* embW = (const float*)d_in[3];
    const float* embB = (const float*)d_in[4];
    const float* gcnW = (const float*)d_in[5];
    const float* gcnB = (const float*)d_in[6];
    const float* rW1  = (const float*)d_in[7];
    const float* rB1  = (const float*)d_in[8];
    const float* rW2  = (const float*)d_in[9];
    const float* rB2  = (const float*)d_in[10];
    const float* hW1  = (const float*)d_in[11];
    const float* hB1  = (const float*)d_in[12];
    const float* hW2  = (const float*)d_in[13];
    const float* hB2  = (const float*)d_in[14];
    const float* hW3  = (const float*)d_in[15];
    const float* hB3  = (const float*)d_in[16];
    float* out = (float*)d_out;

    unsigned short* h0     = (unsigned short*)d_ws;
    unsigned short* h1     = h0 + (size_t)NN * 64;
    int*            srcs   = (int*)(h1 + (size_t)NN * 64);
    int*            rowptr = srcs + NEDGE;
    int*            cnt    = rowptr + NN + 256;
    int*            bsum   = cnt + NN;
    float*          dinv   = (float*)(bsum + 512);
    unsigned short* gcnWt  = (unsigned short*)(dinv + NN);
    unsigned short* rW1t   = gcnWt + 3 * 64 * 64;
    unsigned short* rW2t   = rW1t + 3 * 64 * 256;
    unsigned short* hW1t   = rW2t + 3 * 256 * 64;
    unsigned short* hW2t   = hW1t + 3 * 512 * 256;
    unsigned short* hW3t   = hW2t + 3 * 256 * 128;

    // weight transposes (fp32 [K][M] -> bf16 [M][K], x3 iters each)
    k_trans<<<(3*64*64   + 255)/256, 256, 0, stream>>>(gcnW, gcnWt, 64, 64,  3*64*64);
    k_trans<<<(3*64*256  + 255)/256, 256, 0, stream>>>(rW1,  rW1t,  64, 256, 3*64*256);
    k_trans<<<(3*256*64  + 255)/256, 256, 0, stream>>>(rW2,  rW2t,  256, 64, 3*256*64);
    k_trans<<<(3*512*256 + 255)/256, 256, 0, stream>>>(hW1,  hW1t,  512, 256, 3*512*256);
    k_trans<<<(3*256*128 + 255)/256, 256, 0, stream>>>(hW2,  hW2t,  256, 128, 3*256*128);
    k_trans<<<(3*128*9   + 255)/256, 256, 0, stream>>>(hW3,  hW3t,  128, 9,   3*128*9);

    // CSR build
    k_cnt_init<<<NN / 256, 256, 0, stream>>>(cnt);
    k_hist<<<NEDGE / 256, 256, 0, stream>>>(eidx, cnt);
    k_scan1<<<512, 256, 0, stream>>>(cnt, rowptr, bsum, dinv);
    k_scan2<<<1, 512, 0, stream>>>(bsum);
    k_scan3<<<512, 256, 0, stream>>>(rowptr, bsum, cnt);
    k_fill<<<NEDGE / 256, 256, 0, stream>>>(eidx, cnt, srcs);

    unsigned short* hcur = h0;
    unsigned short* hnxt = h1;
    for (int i = 0; i < NITERS; ++i) {
        unsigned short* hdst = (i == 0) ? h0 : hnxt;
        if (i == 0) {
            k_gcnref<true><<<NN / 64, 256, 0, stream>>>(
                rowptr, srcs, dinv, syn, embW, embB, nullptr,
                gcnWt, gcnB,
                rW1t, rB1, rW2t, rB2, h0);
        } else {
            k_gcnref<false><<<NN / 64, 256, 0, stream>>>(
                rowptr, srcs, dinv, nullptr, nullptr, nullptr, hcur,
                gcnWt + (size_t)i * 64 * 64, gcnB + (size_t)i * 64,
                rW1t + (size_t)i * 64 * 256, rB1 + (size_t)i * 256,
                rW2t + (size_t)i * 256 * 64, rB2 + (size_t)i * 64, hdst);
        }
        k_head<<<NB / 64, 256, 0, stream>>>(hdst,
                                            hW1t + (size_t)i * 512 * 256, hB1 + (size_t)i * 256,
                                            hW2t + (size_t)i * 256 * 128, hB2 + (size_t)i * 128,
                                            hW3t + (size_t)i * 128 * 9,   hB3 + (size_t)i * 9,
                                            out + (size_t)i * NB * NQ);
        if (i == 0) { hcur = h0; hnxt = h1; }
        else { unsigned short* t = hcur; hcur = hdst; hnxt = t; }
    }
}

// Round 9
// 1216.966 us; speedup vs baseline: 21.8533x; 1.0164x over previous
//
#include <hip/hip_runtime.h>
#include <cstdint>

#define NN 524288       // total nodes = B*S
#define NB 65536        // batch
#define NQ 9
#define NEDGE 2097152
#define NITERS 3

typedef __attribute__((ext_vector_type(8))) short bf16x8;
typedef __attribute__((ext_vector_type(4))) float f32x4;

// ---------------- bf16 helpers (bit-level, RNE) ----------------
__device__ __forceinline__ unsigned short f2b(float f) {
    union { float f; unsigned u; } v; v.f = f;
    unsigned u = v.u;
    u += 0x7FFFu + ((u >> 16) & 1u);
    return (unsigned short)(u >> 16);
}
__device__ __forceinline__ float b2f(unsigned short b) {
    union { unsigned u; float f; } v; v.u = ((unsigned)b) << 16;
    return v.f;
}
__device__ __forceinline__ float frelu(float v) { return v > 0.f ? v : 0.f; }

// Swizzled LDS index (ushort units): XOR row&7 into ushort-col bits 3..5.
__device__ __forceinline__ int sw64(int r, int c)  { return r * 64  + (c ^ ((r & 7) << 3)); }

// ---------------- CSR construction ----------------

__global__ void k_cnt_init(int* __restrict__ cnt) {
    cnt[blockIdx.x * 256 + threadIdx.x] = 0;
}

__global__ void k_hist(const int* __restrict__ eidx, int* __restrict__ cnt) {
    int e = blockIdx.x * 256 + threadIdx.x;
    atomicAdd(&cnt[eidx[NEDGE + e]], 1);
}

__global__ void k_scan1(const int* __restrict__ cnt, int* __restrict__ rowptr,
                        int* __restrict__ bsum, float* __restrict__ dinv) {
    __shared__ int sd[256];
    int tid = threadIdx.x;
    int base = (blockIdx.x * 256 + tid) * 4;
    int c0 = cnt[base], c1 = cnt[base + 1], c2 = cnt[base + 2], c3 = cnt[base + 3];
    dinv[base]     = rsqrtf(1.f + (float)c0);
    dinv[base + 1] = rsqrtf(1.f + (float)c1);
    dinv[base + 2] = rsqrtf(1.f + (float)c2);
    dinv[base + 3] = rsqrtf(1.f + (float)c3);
    int t = c0 + c1 + c2 + c3;
    sd[tid] = t; __syncthreads();
    for (int o = 1; o < 256; o <<= 1) {
        int v = (tid >= o) ? sd[tid - o] : 0;
        __syncthreads();
        sd[tid] += v;
        __syncthreads();
    }
    int excl = sd[tid] - t;
    rowptr[base]     = excl;
    rowptr[base + 1] = excl + c0;
    rowptr[base + 2] = excl + c0 + c1;
    rowptr[base + 3] = excl + c0 + c1 + c2;
    if (tid == 255) bsum[blockIdx.x] = sd[255];
}

__global__ void k_scan2(int* __restrict__ bsum) {   // 1 block x 512
    __shared__ int sd[512];
    int tid = threadIdx.x;
    int v = bsum[tid];
    sd[tid] = v; __syncthreads();
    for (int o = 1; o < 512; o <<= 1) {
        int u = (tid >= o) ? sd[tid - o] : 0;
        __syncthreads();
        sd[tid] += u;
        __syncthreads();
    }
    bsum[tid] = sd[tid] - v;   // exclusive
}

__global__ void k_scan3(int* __restrict__ rowptr, const int* __restrict__ bsum,
                        int* __restrict__ cursor) {
    int tid = threadIdx.x;
    int base = (blockIdx.x * 256 + tid) * 4;
    int off = bsum[blockIdx.x];
#pragma unroll
    for (int j = 0; j < 4; ++j) {
        int r = rowptr[base + j] + off;
        rowptr[base + j] = r;
        cursor[base + j] = r;
    }
    if (blockIdx.x == 511 && tid == 255) rowptr[NN] = NEDGE;
}

__global__ void k_fill(const int* __restrict__ eidx, int* __restrict__ cursor,
                       int* __restrict__ srcs) {
    int e = blockIdx.x * 256 + threadIdx.x;
    int s = eidx[e], d = eidx[NEDGE + e];
    int pos = atomicAdd(&cursor[d], 1);
    srcs[pos] = s;
}

// ---------------- weight transpose W[K][M] fp32 -> Wt[M][K] bf16 (x3 iters) ----
__global__ void k_trans(const float* __restrict__ W, unsigned short* __restrict__ Wt,
                        int K, int M, int total) {
    int o = blockIdx.x * 256 + threadIdx.x;
    if (o >= total) return;
    int km = K * M;
    int it = o / km;
    int rem = o - it * km;
    int m = rem / K;
    int k = rem - m * K;
    Wt[o] = f2b(W[(size_t)it * km + (size_t)k * M + m]);
}

// =====================================================================
// Swapped MFMA orientation: A = weights (m = out-col), B = activations
// (n = out-row).  A-frag: Wt[m=base+l&15][kc+(l>>4)*8..+8] row-contig.
// B-frag: act[n=base+l&15][kc+(l>>4)*8..+8] row-contig.
// C: lane holds m=(l>>4)*4+r (4 consecutive out-cols), n=l&15.
// =====================================================================

// ---------------- fused gather + GCN + refine (+ embed for iter 0) --------
// Block = 64 nodes.  LDS: tl 8KB (agg/h' tile, then store-staging) +
// zl 8KB (z quarter-tile) = 16KB.
// Gather lane map: group g = l>>4 owns one node per quad; lane-in-group
// i = l&15 covers feats 4i..4i+3 (ushort4 = 8B; 16 lanes = one 128B row).
// Unroll-8: 8 row-loads in flight per lane (dfast<=16 -> at most 2 iters).

template<bool EMBED>
__global__ __launch_bounds__(256, 6) void k_gcnref(
    const int* __restrict__ rowptr, const int* __restrict__ srcs,
    const float* __restrict__ dinv,
    const float* __restrict__ syn, const float* __restrict__ embW,
    const float* __restrict__ embB,
    const unsigned short* __restrict__ hin,
    const unsigned short* __restrict__ Wgt, const float* __restrict__ bg,
    const unsigned short* __restrict__ W1t, const float* __restrict__ b1,
    const unsigned short* __restrict__ W2t, const float* __restrict__ b2,
    unsigned short* __restrict__ hout)
{
    __shared__ unsigned short tl[64 * 64];    // agg -> h' -> h_out staging
    __shared__ unsigned short zl[64 * 64];    // z quarter-tile
    const int tid = threadIdx.x, wid = tid >> 6, l = tid & 63;
    const int lr = l & 15, lkq = l >> 4;
    const int g = l >> 4, i = l & 15;         // gather roles
    const int rowBase = blockIdx.x * 64;
    const int nb = rowBase + wid * 16;

    float4 ew4, eb4;
    if (EMBED) {
        ew4 = *(const float4*)(embW + i * 4);
        eb4 = *(const float4*)(embB + i * 4);
    }

    // ---- gather: 4 quads of 4 nodes; group g owns node quad*4+g ----
    for (int q = 0; q < 4; ++q) {
        const int node = nb + q * 4 + g;
        int beg = rowptr[node];
        int deg = rowptr[node + 1] - beg;
        int   sl = (i < deg) ? srcs[beg + i] : node;   // pad: self, weight 0
        float wl = (i < deg) ? dinv[sl] : 0.f;

        float dn = dinv[node];
        float a0, a1, a2, a3;
        if (EMBED) {
            float s0 = syn[node];
            a0 = (s0 * ew4.x + eb4.x) * dn;
            a1 = (s0 * ew4.y + eb4.y) * dn;
            a2 = (s0 * ew4.z + eb4.z) * dn;
            a3 = (s0 * ew4.w + eb4.w) * dn;
        } else {
            ushort4 sv = *(const ushort4*)(hin + (size_t)node * 64 + i * 4);
            a0 = b2f(sv.x) * dn; a1 = b2f(sv.y) * dn;
            a2 = b2f(sv.z) * dn; a3 = b2f(sv.w) * dn;
        }

        int dmax = max(max(__shfl(deg, 0), __shfl(deg, 16)),
                       max(__shfl(deg, 32), __shfl(deg, 48)));
        int dfast = dmax < 16 ? dmax : 16;

        // unroll-8: pu = p+u <= 15 always, pad lanes already carry (self, 0)
        for (int p = 0; p < dfast; p += 8) {
            int   s[8]; float w[8];
#pragma unroll
            for (int u = 0; u < 8; ++u) {
                int idx = (l & 48) + p + u;
                s[u] = __shfl(sl, idx);
                w[u] = __shfl(wl, idx);
            }
            if (EMBED) {
                float sy[8];
#pragma unroll
                for (int u = 0; u < 8; ++u) sy[u] = syn[s[u]];
#pragma unroll
                for (int u = 0; u < 8; ++u) {
                    a0 += (sy[u] * ew4.x + eb4.x) * w[u];
                    a1 += (sy[u] * ew4.y + eb4.y) * w[u];
                    a2 += (sy[u] * ew4.z + eb4.z) * w[u];
                    a3 += (sy[u] * ew4.w + eb4.w) * w[u];
                }
            } else {
                ushort4 v[8];
#pragma unroll
                for (int u = 0; u < 8; ++u)
                    v[u] = *(const ushort4*)(hin + (size_t)s[u] * 64 + i * 4);
#pragma unroll
                for (int u = 0; u < 8; ++u) {
                    a0 += b2f(v[u].x) * w[u];
                    a1 += b2f(v[u].y) * w[u];
                    a2 += b2f(v[u].z) * w[u];
                    a3 += b2f(v[u].w) * w[u];
                }
            }
        }
        if (deg > 16) {                         // vanishingly rare tail (group-uniform)
            for (int t = 16; t < deg; ++t) {
                int st = srcs[beg + t];
                float wt = dinv[st];
                if (EMBED) {
                    float sy = syn[st];
                    a0 += (sy * ew4.x + eb4.x) * wt;
                    a1 += (sy * ew4.y + eb4.y) * wt;
                    a2 += (sy * ew4.z + eb4.z) * wt;
                    a3 += (sy * ew4.w + eb4.w) * wt;
                } else {
                    ushort4 v = *(const ushort4*)(hin + (size_t)st * 64 + i * 4);
                    a0 += b2f(v.x) * wt; a1 += b2f(v.y) * wt;
                    a2 += b2f(v.z) * wt; a3 += b2f(v.w) * wt;
                }
            }
        }
        ushort4 o;
        o.x = f2b(a0 * dn); o.y = f2b(a1 * dn);
        o.z = f2b(a2 * dn); o.w = f2b(a3 * dn);
        *(ushort4*)&tl[sw64(wid * 16 + q * 4 + g, i * 4)] = o;
    }
    // no barrier: GCN below reads only this wave's own 16 rows

    // ---- GCN: h' = relu(agg @ Wg + bg); wave computes its own 16 rows ----
    f32x4 ag[4];
#pragma unroll
    for (int mg = 0; mg < 4; ++mg) ag[mg] = (f32x4){0.f, 0.f, 0.f, 0.f};
#pragma unroll
    for (int kc = 0; kc < 64; kc += 32) {
        bf16x8 bfr = *(const bf16x8*)&tl[sw64(wid * 16 + lr, kc + lkq * 8)];
#pragma unroll
        for (int mg = 0; mg < 4; ++mg) {
            bf16x8 a = *(const bf16x8*)(Wgt + (size_t)(mg * 16 + lr) * 64 + kc + lkq * 8);
            ag[mg] = __builtin_amdgcn_mfma_f32_16x16x32_bf16(a, bfr, ag[mg], 0, 0, 0);
        }
    }
#pragma unroll
    for (int mg = 0; mg < 4; ++mg) {
        int m0 = mg * 16 + lkq * 4;
        float4 bb = *(const float4*)(bg + m0);
        ushort4 o;
        o.x = f2b(frelu(ag[mg][0] + bb.x));
        o.y = f2b(frelu(ag[mg][1] + bb.y));
        o.z = f2b(frelu(ag[mg][2] + bb.z));
        o.w = f2b(frelu(ag[mg][3] + bb.w));
        *(ushort4*)&tl[sw64(wid * 16 + lr, m0)] = o;   // overwrite own rows with h'
    }
    __syncthreads();

    // ---- refine in four 64-col quarters; r2 accumulates across quarters ----
    f32x4 r2[4];
#pragma unroll
    for (int mg = 0; mg < 4; ++mg) r2[mg] = (f32x4){0.f, 0.f, 0.f, 0.f};

#pragma unroll
    for (int qt = 0; qt < 4; ++qt) {
        // R1 quarter: z cols qt*64..+64; this wave computes 16 of them
        f32x4 z1a[4];
#pragma unroll
        for (int ng = 0; ng < 4; ++ng) z1a[ng] = (f32x4){0.f, 0.f, 0.f, 0.f};
#pragma unroll
        for (int kc = 0; kc < 64; kc += 32) {
            bf16x8 a = *(const bf16x8*)(W1t +
                (size_t)(qt * 64 + wid * 16 + lr) * 64 + kc + lkq * 8);
#pragma unroll
            for (int ng = 0; ng < 4; ++ng) {
                bf16x8 bfr = *(const bf16x8*)&tl[sw64(ng * 16 + lr, kc + lkq * 8)];
                z1a[ng] = __builtin_amdgcn_mfma_f32_16x16x32_bf16(a, bfr, z1a[ng], 0, 0, 0);
            }
        }
        {
            int m0 = wid * 16 + lkq * 4;                 // local col within quarter
            float4 bb = *(const float4*)(b1 + qt * 64 + m0);
#pragma unroll
            for (int ng = 0; ng < 4; ++ng) {
                int n = ng * 16 + lr;
                ushort4 o;
                o.x = f2b(frelu(z1a[ng][0] + bb.x));
                o.y = f2b(frelu(z1a[ng][1] + bb.y));
                o.z = f2b(frelu(z1a[ng][2] + bb.z));
                o.w = f2b(frelu(z1a[ng][3] + bb.w));
                *(ushort4*)&zl[sw64(n, m0)] = o;
            }
        }
        __syncthreads();

        // R2 partial: accumulate k = qt*64 .. +64
#pragma unroll
        for (int kc = 0; kc < 64; kc += 32) {
            bf16x8 bz = *(const bf16x8*)&zl[sw64(wid * 16 + lr, kc + lkq * 8)];
#pragma unroll
            for (int mg = 0; mg < 4; ++mg) {
                bf16x8 a = *(const bf16x8*)(W2t +
                    (size_t)(mg * 16 + lr) * 256 + qt * 64 + kc + lkq * 8);
                r2[mg] = __builtin_amdgcn_mfma_f32_16x16x32_bf16(a, bz, r2[mg], 0, 0, 0);
            }
        }
        if (qt < 3) __syncthreads();   // before next quarter overwrites zl
    }

    // ---- epilogue: h = relu(h' + r + b2) -> stage in tl, then full-line copy ----
    {
        int n = wid * 16 + lr;
#pragma unroll
        for (int mg = 0; mg < 4; ++mg) {
            int m0 = mg * 16 + lkq * 4;
            float4 bb = *(const float4*)(b2 + m0);
            ushort4 rs = *(const ushort4*)&tl[sw64(n, m0)];
            ushort4 o;
            o.x = f2b(frelu(r2[mg][0] + bb.x + b2f(rs.x)));
            o.y = f2b(frelu(r2[mg][1] + bb.y + b2f(rs.y)));
            o.z = f2b(frelu(r2[mg][2] + bb.z + b2f(rs.z)));
            o.w = f2b(frelu(r2[mg][3] + bb.w + b2f(rs.w)));
            *(ushort4*)&tl[sw64(n, m0)] = o;
        }
    }
    __syncthreads();
    {
        int r = tid >> 2, c16 = (tid & 3) * 16;     // 32 B per thread, full lines per 4 threads
        bf16x8 v0 = *(const bf16x8*)&tl[sw64(r, c16)];
        bf16x8 v1 = *(const bf16x8*)&tl[sw64(r, c16 + 8)];
        *(bf16x8*)(hout + (size_t)(rowBase + r) * 64 + c16) = v0;
        *(bf16x8*)(hout + (size_t)(rowBase + r) * 64 + c16 + 8) = v1;
    }
}

// ---------------- fused head: out = sig(relu(relu(hall@W1)@W2)@W3) ----------
__global__ __launch_bounds__(256) void k_head(const unsigned short* __restrict__ hb,   // [NB][512]
                                              const unsigned short* __restrict__ W1t,  // [256][512]
                                              const float* __restrict__ b1,
                                              const unsigned short* __restrict__ W2t,  // [128][256]
                                              const float* __restrict__ b2,
                                              const unsigned short* __restrict__ W3t,  // [9][128]
                                              const float* __restrict__ b3,
                                              float* __restrict__ out) {
    __shared__ unsigned short z1[64][280];
    __shared__ unsigned short z2[64][152];
    const int tid = threadIdx.x, wid = tid >> 6, l = tid & 63;
    const int lr = l & 15, lkq = l >> 4;
    const unsigned short* hall = hb + (size_t)blockIdx.x * 64 * 512;

    // GEMM1: z1[n][m], m in wid*64..+64, n all 64, K=512
    f32x4 acc1[4][4];
#pragma unroll
    for (int mg = 0; mg < 4; ++mg)
#pragma unroll
        for (int ng = 0; ng < 4; ++ng) acc1[mg][ng] = (f32x4){0.f, 0.f, 0.f, 0.f};

    for (int kc = 0; kc < 512; kc += 32) {
        bf16x8 bfr[4];
#pragma unroll
        for (int ng = 0; ng < 4; ++ng)
            bfr[ng] = *(const bf16x8*)(hall + (size_t)(ng * 16 + lr) * 512 + kc + lkq * 8);
#pragma unroll
        for (int mg = 0; mg < 4; ++mg) {
            bf16x8 a = *(const bf16x8*)(W1t + (size_t)(wid * 64 + mg * 16 + lr) * 512 + kc + lkq * 8);
#pragma unroll
            for (int ng = 0; ng < 4; ++ng)
                acc1[mg][ng] = __builtin_amdgcn_mfma_f32_16x16x32_bf16(a, bfr[ng], acc1[mg][ng], 0, 0, 0);
        }
    }
#pragma unroll
    for (int mg = 0; mg < 4; ++mg) {
        int m0 = wid * 64 + mg * 16 + lkq * 4;
        float4 bb = *(const float4*)(b1 + m0);
#pragma unroll
        for (int ng = 0; ng < 4; ++ng) {
            int n = ng * 16 + lr;
            ushort4 o;
            o.x = f2b(frelu(acc1[mg][ng][0] + bb.x));
            o.y = f2b(frelu(acc1[mg][ng][1] + bb.y));
            o.z = f2b(frelu(acc1[mg][ng][2] + bb.z));
            o.w = f2b(frelu(acc1[mg][ng][3] + bb.w));
            *(ushort4*)&z1[n][m0] = o;
        }
    }
    __syncthreads();

    // GEMM2: z2[n][m], m in wid*32..+32, n all 64, K=256
    f32x4 acc2[2][4];
#pragma unroll
    for (int mg = 0; mg < 2; ++mg)
#pragma unroll
        for (int ng = 0; ng < 4; ++ng) acc2[mg][ng] = (f32x4){0.f, 0.f, 0.f, 0.f};
#pragma unroll
    for (int kc = 0; kc < 256; kc += 32) {
        bf16x8 bfr[4];
#pragma unroll
        for (int ng = 0; ng < 4; ++ng)
            bfr[ng] = *(const bf16x8*)&z1[ng * 16 + lr][kc + lkq * 8];
#pragma unroll
        for (int mg = 0; mg < 2; ++mg) {
            bf16x8 a = *(const bf16x8*)(W2t + (size_t)(wid * 32 + mg * 16 + lr) * 256 + kc + lkq * 8);
#pragma unroll
            for (int ng = 0; ng < 4; ++ng)
                acc2[mg][ng] = __builtin_amdgcn_mfma_f32_16x16x32_bf16(a, bfr[ng], acc2[mg][ng], 0, 0, 0);
        }
    }
#pragma unroll
    for (int mg = 0; mg < 2; ++mg) {
        int m0 = wid * 32 + mg * 16 + lkq * 4;
        float4 bb = *(const float4*)(b2 + m0);
#pragma unroll
        for (int ng = 0; ng < 4; ++ng) {
            int n = ng * 16 + lr;
            ushort4 o;
            o.x = f2b(frelu(acc2[mg][ng][0] + bb.x));
            o.y = f2b(frelu(acc2[mg][ng][1] + bb.y));
            o.z = f2b(frelu(acc2[mg][ng][2] + bb.z));
            o.w = f2b(frelu(acc2[mg][ng][3] + bb.w));
            *(ushort4*)&z2[n][m0] = o;
        }
    }
    __syncthreads();

    // GEMM3: out[n][m<9], wave owns n = wid*16..+16, K=128
    f32x4 acc3 = (f32x4){0.f, 0.f, 0.f, 0.f};
    int arow = lr < 9 ? lr : 8;
#pragma unroll
    for (int kc = 0; kc < 128; kc += 32) {
        bf16x8 bz = *(const bf16x8*)&z2[wid * 16 + lr][kc + lkq * 8];
        bf16x8 a = *(const bf16x8*)(W3t + (size_t)arow * 128 + kc + lkq * 8);
        acc3 = __builtin_amdgcn_mfma_f32_16x16x32_bf16(a, bz, acc3, 0, 0, 0);
    }
    {
        long shot = (long)blockIdx.x * 64 + wid * 16 + lr;
#pragma unroll
        for (int r = 0; r < 4; ++r) {
            int m = lkq * 4 + r;
            if (m < 9) {
                float v = acc3[r] + b3[m];
                out[shot * 9 + m] = 1.f / (1.f + expf(-v));
            }
        }
    }
}

// ---------------- launcher ----------------
// Workspace (~144 MB): h0 67MB | h1 67MB | srcs 8.4MB | rowptr/cnt/bsum/dinv | Wt 1.2MB

extern "C" void kernel_launch(void* const* d_in, const int* in_sizes, int n_in,
                              void* d_out, int out_size, void* d_ws, size_t ws_size,
                              hipStream_t stream) {
    const float* syn  = (const float*)d_in[0];
    const int*   eidx = (const int*)d_in[1];
    const float* embW = (const float*)d_in[3];
    const float* embB = (const float*)d_in[4];
    const float* gcnW = (const float*)d_in[5];
    const float* gcnB = (const float*)d_in[6];
    const float* rW1  = (const float*)d_in[7];
    const float* rB1  = (const float*)d_in[8];
    const float* rW2  = (const float*)d_in[9];
    const float* rB2  = (const float*)d_in[10];
    const float* hW1  = (const float*)d_in[11];
    const float* hB1  = (const float*)d_in[12];
    const float* hW2  = (const float*)d_in[13];
    const float* hB2  = (const float*)d_in[14];
    const float* hW3  = (const float*)d_in[15];
    const float* hB3  = (const float*)d_in[16];
    float* out = (float*)d_out;

    unsigned short* h0     = (unsigned short*)d_ws;
    unsigned short* h1     = h0 + (size_t)NN * 64;
    int*            srcs   = (int*)(h1 + (size_t)NN * 64);
    int*            rowptr = srcs + NEDGE;
    int*            cnt    = rowptr + NN + 256;
    int*            bsum   = cnt + NN;
    float*          dinv   = (float*)(bsum + 512);
    unsigned short* gcnWt  = (unsigned short*)(dinv + NN);
    unsigned short* rW1t   = gcnWt + 3 * 64 * 64;
    unsigned short* rW2t   = rW1t + 3 * 64 * 256;
    unsigned short* hW1t   = rW2t + 3 * 256 * 64;
    unsigned short* hW2t   = hW1t + 3 * 512 * 256;
    unsigned short* hW3t   = hW2t + 3 * 256 * 128;

    // weight transposes (fp32 [K][M] -> bf16 [M][K], x3 iters each)
    k_trans<<<(3*64*64   + 255)/256, 256, 0, stream>>>(gcnW, gcnWt, 64, 64,  3*64*64);
    k_trans<<<(3*64*256  + 255)/256, 256, 0, stream>>>(rW1,  rW1t,  64, 256, 3*64*256);
    k_trans<<<(3*256*64  + 255)/256, 256, 0, stream>>>(rW2,  rW2t,  256, 64, 3*256*64);
    k_trans<<<(3*512*256 + 255)/256, 256, 0, stream>>>(hW1,  hW1t,  512, 256, 3*512*256);
    k_trans<<<(3*256*128 + 255)/256, 256, 0, stream>>>(hW2,  hW2t,  256, 128, 3*256*128);
    k_trans<<<(3*128*9   + 255)/256, 256, 0, stream>>>(hW3,  hW3t,  128, 9,   3*128*9);

    // CSR build
    k_cnt_init<<<NN / 256, 256, 0, stream>>>(cnt);
    k_hist<<<NEDGE / 256, 256, 0, stream>>>(eidx, cnt);
    k_scan1<<<512, 256, 0, stream>>>(cnt, rowptr, bsum, dinv);
    k_scan2<<<1, 512, 0, stream>>>(bsum);
    k_scan3<<<512, 256, 0, stream>>>(rowptr, bsum, cnt);
    k_fill<<<NEDGE / 256, 256, 0, stream>>>(eidx, cnt, srcs);

    unsigned short* hcur = h0;
    unsigned short* hnxt = h1;
    for (int i = 0; i < NITERS; ++i) {
        unsigned short* hdst = (i == 0) ? h0 : hnxt;
        if (i == 0) {
            k_gcnref<true><<<NN / 64, 256, 0, stream>>>(
                rowptr, srcs, dinv, syn, embW, embB, nullptr,
                gcnWt, gcnB,
                rW1t, rB1, rW2t, rB2, h0);
        } else {
            k_gcnref<false><<<NN / 64, 256, 0, stream>>>(
                rowptr, srcs, dinv, nullptr, nullptr, nullptr, hcur,
                gcnWt + (size_t)i * 64 * 64, gcnB + (size_t)i * 64,
                rW1t + (size_t)i * 64 * 256, rB1 + (size_t)i * 256,
                rW2t + (size_t)i * 256 * 64, rB2 + (size_t)i * 64, hdst);
        }
        k_head<<<NB / 64, 256, 0, stream>>>(hdst,
                                            hW1t + (size_t)i * 512 * 256, hB1 + (size_t)i * 256,
                                            hW2t + (size_t)i * 256 * 128, hB2 + (size_t)i * 128,
                                            hW3t + (size_t)i * 128 * 9,   hB3 + (size_t)i * 9,
                                            out + (size_t)i * NB * NQ);
        if (i == 0) { hcur = h0; hnxt = h1; }
        else { unsigned short* t = hcur; hcur = hdst; hnxt = t; }
    }
}